// Round 9
// baseline (1270.103 us; speedup 1.0000x reference)
//
#include <hip/hip_runtime.h>
#include <hip/hip_bf16.h>
#include <math.h>

// ---------------------------------------------------------------------------
// TAPIR forward. State f32; cv + mixer GEMMs + hid2/hid3 convs via bf16 MFMA.
// fg[64,64,256] hg[128,128,128] qf[1024,256] hq[1024,128] -> out[1024,4]
// 3 dispatches: prep+cv, head stripes, persistent refine (manual grid barrier;
// phase bodies identical to the round-6 split kernels, grid-strided).
// ---------------------------------------------------------------------------

#define NQ 1024
#define TEMPF 20.0f
#define DIMV 388
#define INDIM 535
#define KPAD 544
#define HID 512

// workspace layout (float offsets)
#define WS_CVB     0
#define WS_WIT     2097152                    // bf16 [512][544]
#define WS_WOT     2236416                    // bf16 [448][512]
#define WS_FG16    2351104                    // bf16 fg copy (1048576)
#define WS_HG16    2875392                    // bf16 hg copy (2097152)
#define WS_AV16    3923968                    // bf16 fgavg copy (262144)
#define WS_FGAVG   4194304                    // dead region; hosts barrier state
#define WS_BAR     (WS_FGAVG + 1024)          // 32 ints: 16 leaf, root, gen
#define WS_POS     (WS_FGAVG + 262144)
#define WS_OCC     (WS_POS + NQ*2)
#define WS_EXPD    (WS_OCC + NQ)
#define WS_FEATS   (WS_EXPD + NQ)             // f32 [1024][384]
#define WS_MLPIN   (WS_FEATS + NQ*384)        // bf16 mlp_in [1024][544]
#define WS_HIDDEN  (WS_MLPIN + NQ*KPAD)       // bf16 hidden [1024][512] / SUM3
#define WS_W3B     (WS_HIDDEN + NQ*HID)       // bf16 hid3 B-fragments (5120)
#define WS_W2B     (WS_W3B + 2560)            // bf16 hid2 B-fragments (2560)
#define WS_PART    (WS_MLPIN + 278528)        // softmax partials overlay
#define WS_SUM3    WS_HIDDEN                  // hid3 relu-sums overlay

#define CVP 68                                // cvs LDS pitch
#define ROWP 2368                             // occ_t row pitch bytes

typedef __attribute__((ext_vector_type(8))) short bf16x8;
typedef __attribute__((ext_vector_type(4))) float f32x4;

union BU8 { uint4 u; __hip_bfloat16 h[8]; };

__device__ __forceinline__ int occ_off(int r, int idx, int c) {
  int o = idx * 32 + c * 2;
  o ^= ((idx >> 2) & 3) << 4;
  return r * ROWP + o;
}

// ---------------------------------------------------------------------------
// fused prep + cost volume + all bf16 conversions (round-6 body + barrier
// state zeroing).
// ---------------------------------------------------------------------------
__global__ __launch_bounds__(256) void k_prep_cv(
    const float* __restrict__ fg, const float* __restrict__ hg,
    const float* __restrict__ qf, const float* __restrict__ hq,
    const float* __restrict__ w3, const float* __restrict__ w2,
    const float* __restrict__ wi, const float* __restrict__ wo,
    float* __restrict__ ws) {
  __shared__ __hip_bfloat16 A_s[32 * 32];
  __shared__ __hip_bfloat16 B_s[64 * 32];
  const int bx = blockIdx.x;
  const int t = threadIdx.x;

  if (bx >= 2048) {
    int i = (bx - 2048) * 256 + t;
    if (i < 32) ((int*)(ws + WS_BAR))[i] = 0;   // grid-barrier state
    if (i < 262144) {
      int c = i & 255, ox = (i >> 8) & 31, oy = i >> 13;
      const float* b = fg + (((oy * 2) * 64 + ox * 2) << 8) + c;
      float av = 0.25f * (b[0] + b[256] + b[16384] + b[16384 + 256]);
      ((__hip_bfloat16*)(ws + WS_AV16))[i] = __float2bfloat16(av);
    } else if (i < 655360) {
      int j = i - 262144;
      int n = j / 384, c = j - n * 384;
      float v = (c < 128) ? hq[n * 128 + c] : qf[n * 256 + c - 128];
      ws[WS_FEATS + j] = v;
      __hip_bfloat16* mi = (__hip_bfloat16*)(ws + WS_MLPIN);
      mi[n * KPAD + 4 + c] = __float2bfloat16(v);
      if (c == 0) {
        mi[n * KPAD + 0] = __float2bfloat16(0.f);
        mi[n * KPAD + 1] = __float2bfloat16(0.f);
      }
    } else if (i < 660480) {
      int j = i - 655360;
      int e = j & 7, qd = (j >> 3) & 3, nl = (j >> 5) & 15;
      int nt = (j >> 9) & 1, kt = j >> 10;
      int k = kt * 32 + qd * 8 + e;
      int ic = k & 15, tap = k >> 4;
      int oc = nt * 16 + nl;
      float v = (tap < 9) ? w3[(oc * 16 + ic) * 9 + tap] : 0.f;
      ((__hip_bfloat16*)(ws + WS_W3B))[j] = __float2bfloat16(v);
    } else if (i < 663040) {
      int j = i - 660480;
      int e = j & 7, qd = (j >> 3) & 3, kt = j >> 9;
      int k = kt * 32 + qd * 8 + e;
      int ch = k & 15, tap = k >> 4;
      float v = (tap < 9) ? w2[ch * 9 + tap] : 0.f;
      ((__hip_bfloat16*)(ws + WS_W2B))[j] = __float2bfloat16(v);
    } else if (i < 1187328) {
      ws[WS_SUM3 + (i - 663040)] = 0.f;
    } else if (i < 1465856) {
      int j = i - 1187328;
      int n = j / KPAD, k = j - n * KPAD;
      float v = (k < INDIM) ? wi[k * HID + n] : 0.f;
      ((__hip_bfloat16*)(ws + WS_WIT))[j] = __float2bfloat16(v);
    } else if (i < 1695232) {
      int j = i - 1465856;
      int n = j >> 9, k = j & 511;
      float v = (n < DIMV) ? wo[k * DIMV + n] : 0.f;
      ((__hip_bfloat16*)(ws + WS_WOT))[j] = __float2bfloat16(v);
    } else if (i < 1957376) {
      int j = (i - 1695232) * 4;
      float4 v = *(const float4*)&fg[j];
      union { __hip_bfloat16 h[4]; uint2 u; } pk;
      pk.h[0] = __float2bfloat16(v.x); pk.h[1] = __float2bfloat16(v.y);
      pk.h[2] = __float2bfloat16(v.z); pk.h[3] = __float2bfloat16(v.w);
      *(uint2*)(((__hip_bfloat16*)(ws + WS_FG16)) + j) = pk.u;
    } else {
      int j = (i - 1957376) * 4;
      float4 v = *(const float4*)&hg[j];
      union { __hip_bfloat16 h[4]; uint2 u; } pk;
      pk.h[0] = __float2bfloat16(v.x); pk.h[1] = __float2bfloat16(v.y);
      pk.h[2] = __float2bfloat16(v.z); pk.h[3] = __float2bfloat16(v.w);
      *(uint2*)(((__hip_bfloat16*)(ws + WS_HG16)) + j) = pk.u;
    }
    return;
  }

  // ---- cv part ----
  const int wv = t >> 6, lane = t & 63;
  const int wm = wv & 1, wn = wv >> 1;
  const int quad = lane >> 4, nl = lane & 15;
  const int p0 = (bx & 63) * 64, m0 = (bx >> 6) * 32;
  f32x4 acc0 = {0.f, 0.f, 0.f, 0.f};
  f32x4 acc1 = {0.f, 0.f, 0.f, 0.f};

  for (int k0 = 0; k0 < 256; k0 += 32) {
    {
      int r = t >> 3, c = t & 7;
      float4 v = *(const float4*)&qf[(m0 + r) * 256 + k0 + c * 4];
      union { __hip_bfloat16 h[4]; uint2 u; } pk;
      pk.h[0] = __float2bfloat16(v.x); pk.h[1] = __float2bfloat16(v.y);
      pk.h[2] = __float2bfloat16(v.z); pk.h[3] = __float2bfloat16(v.w);
      *(uint2*)&A_s[r * 32 + c * 4] = pk.u;
    }
    {
      int r = t >> 2, c = t & 3;
      const float* src = &fg[(p0 + r) * 256 + k0 + c * 8];
      float4 v0 = *(const float4*)src;
      float4 v1 = *(const float4*)(src + 4);
      union { __hip_bfloat16 h[8]; uint4 u; } pk;
      pk.h[0] = __float2bfloat16(v0.x); pk.h[1] = __float2bfloat16(v0.y);
      pk.h[2] = __float2bfloat16(v0.z); pk.h[3] = __float2bfloat16(v0.w);
      pk.h[4] = __float2bfloat16(v1.x); pk.h[5] = __float2bfloat16(v1.y);
      pk.h[6] = __float2bfloat16(v1.z); pk.h[7] = __float2bfloat16(v1.w);
      *(uint4*)&B_s[r * 32 + c * 8] = pk.u;
    }
    __syncthreads();
    bf16x8 a = *(const bf16x8*)&A_s[(16 * wm + nl) * 32 + quad * 8];
    bf16x8 b0 = *(const bf16x8*)&B_s[(32 * wn + nl) * 32 + quad * 8];
    bf16x8 b1 = *(const bf16x8*)&B_s[(32 * wn + 16 + nl) * 32 + quad * 8];
    acc0 = __builtin_amdgcn_mfma_f32_16x16x32_bf16(a, b0, acc0, 0, 0, 0);
    acc1 = __builtin_amdgcn_mfma_f32_16x16x32_bf16(a, b1, acc1, 0, 0, 0);
    __syncthreads();
  }
  __hip_bfloat16* cvb = (__hip_bfloat16*)ws;
#pragma unroll
  for (int nt = 0; nt < 2; nt++) {
    int n = p0 + 32 * wn + nt * 16 + nl;
#pragma unroll
    for (int r = 0; r < 4; r++) {
      int m = m0 + 16 * wm + quad * 4 + r;
      cvb[m * 4096 + n] = __float2bfloat16(nt ? acc1[r] : acc0[r]);
    }
  }
}

// ---------------------------------------------------------------------------
// head stripe kernel (unchanged from round 6): 16384 blocks.
// ---------------------------------------------------------------------------
__global__ __launch_bounds__(256, 5) void k_head_stripe(
    const float* __restrict__ h1w, const float* __restrict__ h1b,
    const float* __restrict__ h2b, const float* __restrict__ h3b,
    float* __restrict__ ws) {
  __shared__ float cvs[8 * CVP];
  __shared__ float4 occ_t4[6 * ROWP / 16];
  char* occ_t = (char*)occ_t4;

  const int bx = blockIdx.x;
  const int q = bx >> 4, st = bx & 15;
  const int y0 = st * 4;
  const int t = threadIdx.x;
  const int wv = t >> 6, lane = t & 63;
  const int role = (wv + bx) & 3;
  const __hip_bfloat16* cvb = (const __hip_bfloat16*)ws + q * 4096;

  if (t < 192) {
    int r = t >> 5, j = t & 31;
    int off = r * ROWP + ((j < 16) ? j * 8 : 2176 + (j - 16) * 8);
    *(uint2*)(occ_t + off) = make_uint2(0u, 0u);
  }
  if (st == 0 || st == 15) {
    int r = (st == 0) ? 0 : 5;
    for (int i = t; i < 288; i += 256)
      *(uint2*)(occ_t + r * ROWP + i * 8) = make_uint2(0u, 0u);
  }
#pragma unroll
  for (int j = 0; j < 2; j++) {
    int i = t + 256 * j;
    int lr = i >> 6, x = i & 63;
    int g = y0 - 2 + lr;
    cvs[lr * CVP + x + 1] =
        (g >= 0 && g < 64) ? __bfloat162float(cvb[g * 64 + x]) : 0.f;
  }
  if (t < 32) {
    int rr = t >> 2, c = t & 3;
    cvs[rr * CVP + ((c == 0) ? 0 : (64 + c))] = 0.f;
  }
  __syncthreads();

  {
    const int x = lane;
    const int chg = wv * 4;
    float w1r[4][9], b1r[4];
#pragma unroll
    for (int k = 0; k < 4; k++) {
      b1r[k] = h1b[chg + k];
#pragma unroll
      for (int j = 0; j < 9; j++) w1r[k][j] = h1w[(chg + k) * 9 + j];
    }
    float win[3][3];
#pragma unroll
    for (int j = 0; j < 3; j++) {
      const float* cp = &cvs[j * CVP + x];
      win[j][0] = cp[0]; win[j][1] = cp[1]; win[j][2] = cp[2];
    }
    for (int r = 0; r < 6; r++) {
      if (r > 0) {
#pragma unroll
        for (int c = 0; c < 3; c++) { win[0][c] = win[1][c]; win[1][c] = win[2][c]; }
        const float* cp = &cvs[(r + 2) * CVP + x];
        win[2][0] = cp[0]; win[2][1] = cp[1]; win[2][2] = cp[2];
      }
      int yo = y0 - 1 + r;
      if (yo >= 0 && yo <= 63) {
        union { __hip_bfloat16 h[4]; uint2 u; } pk;
#pragma unroll
        for (int k = 0; k < 4; k++) {
          float a = b1r[k];
#pragma unroll
          for (int ky = 0; ky < 3; ky++)
            a += w1r[k][3 * ky] * win[ky][0] + w1r[k][3 * ky + 1] * win[ky][1] +
                 w1r[k][3 * ky + 2] * win[ky][2];
          pk.h[k] = __float2bfloat16(fmaxf(a, 0.f));
        }
        *(uint2*)(occ_t + occ_off(r, x + 4, chg)) = pk.u;
      }
    }
  }
  __syncthreads();

  const int nl = lane & 15;
  const int qd = lane >> 4, qh = qd >> 1, ql = qd & 1;

  if (role == 1 || role == 2) {
    const __hip_bfloat16* W3B = (const __hip_bfloat16*)(ws + WS_W3B);
    const int oyl = role - 1;
    f32x4 acc00 = {0.f,0.f,0.f,0.f}, acc01 = {0.f,0.f,0.f,0.f};
    f32x4 acc10 = {0.f,0.f,0.f,0.f}, acc11 = {0.f,0.f,0.f,0.f};
#pragma unroll
    for (int kt = 0; kt < 5; kt++) {
      int tap = kt * 2 + qh;
      bf16x8 a0, a1;
      if (tap < 9) {
        int ky = (tap >= 6) ? 2 : ((tap >= 3) ? 1 : 0);
        int kx = tap - 3 * ky;
        int R = 2 * oyl + 1 + ky;
        int idx0 = 4 + kx + 2 * nl;
        a0 = *(const bf16x8*)(occ_t + occ_off(R, idx0, ql * 8));
        a1 = *(const bf16x8*)(occ_t + occ_off(R, idx0 + 32, ql * 8));
      } else {
        a0 = (bf16x8){0, 0, 0, 0, 0, 0, 0, 0};
        a1 = a0;
      }
      bf16x8 b0 = *(const bf16x8*)&W3B[((kt * 2 + 0) * 16 + nl) * 32 + qd * 8];
      bf16x8 b1 = *(const bf16x8*)&W3B[((kt * 2 + 1) * 16 + nl) * 32 + qd * 8];
      acc00 = __builtin_amdgcn_mfma_f32_16x16x32_bf16(a0, b0, acc00, 0, 0, 0);
      acc01 = __builtin_amdgcn_mfma_f32_16x16x32_bf16(a0, b1, acc01, 0, 0, 0);
      acc10 = __builtin_amdgcn_mfma_f32_16x16x32_bf16(a1, b0, acc10, 0, 0, 0);
      acc11 = __builtin_amdgcn_mfma_f32_16x16x32_bf16(a1, b1, acc11, 0, 0, 0);
    }
    float bb0 = h3b[nl], bb1 = h3b[16 + nl];
    float s0 = 0.f, s1 = 0.f;
#pragma unroll
    for (int r = 0; r < 4; r++) {
      s0 += fmaxf(acc00[r] + bb0, 0.f) + fmaxf(acc10[r] + bb0, 0.f);
      s1 += fmaxf(acc01[r] + bb1, 0.f) + fmaxf(acc11[r] + bb1, 0.f);
    }
    s0 += __shfl_xor(s0, 16); s0 += __shfl_xor(s0, 32);
    s1 += __shfl_xor(s1, 16); s1 += __shfl_xor(s1, 32);
    if (lane < 16) {
      atomicAdd(&ws[WS_SUM3 + (q * 16 + st) * 32 + nl], s0);
      atomicAdd(&ws[WS_SUM3 + (q * 16 + st) * 32 + 16 + nl], s1);
    }
  } else {
    const int rl0 = (role == 3) ? 2 : 0;
    const __hip_bfloat16* W2B = (const __hip_bfloat16*)(ws + WS_W2B);
    bf16x8 wb0 = *(const bf16x8*)&W2B[(0 * 16 + nl) * 32 + qd * 8];
    bf16x8 wb1 = *(const bf16x8*)&W2B[(1 * 16 + nl) * 32 + qd * 8];
    bf16x8 wb2 = *(const bf16x8*)&W2B[(2 * 16 + nl) * 32 + qd * 8];
    bf16x8 wb3 = *(const bf16x8*)&W2B[(3 * 16 + nl) * 32 + qd * 8];
    bf16x8 wb4 = *(const bf16x8*)&W2B[(4 * 16 + nl) * 32 + qd * 8];
    f32x4 pa0 = {0.f,0.f,0.f,0.f}, pa1 = {0.f,0.f,0.f,0.f};
    f32x4 pa2 = {0.f,0.f,0.f,0.f}, pa3 = {0.f,0.f,0.f,0.f};
    f32x4 pa4 = {0.f,0.f,0.f,0.f}, pa5 = {0.f,0.f,0.f,0.f};
    f32x4 pa6 = {0.f,0.f,0.f,0.f}, pa7 = {0.f,0.f,0.f,0.f};

#define H2STEP(ACC, ROW, XT, KT, WB)                                         \
    {                                                                        \
      int tap = (KT) * 2 + qh;                                               \
      bf16x8 a;                                                              \
      if (tap < 9) {                                                         \
        int ky = (tap >= 6) ? 2 : ((tap >= 3) ? 1 : 0);                      \
        int kx = tap - 3 * ky;                                               \
        a = *(const bf16x8*)(occ_t +                                         \
            occ_off((ROW) + ky, (XT) + nl + 3 + kx, ql * 8));                \
      } else { a = (bf16x8){0, 0, 0, 0, 0, 0, 0, 0}; }                       \
      ACC = __builtin_amdgcn_mfma_f32_16x16x32_bf16(a, WB, ACC, 0, 0, 0);    \
    }
#define H2TILE(ACC, ROW, XT)                                                 \
    H2STEP(ACC, ROW, XT, 0, wb0) H2STEP(ACC, ROW, XT, 1, wb1)                \
    H2STEP(ACC, ROW, XT, 2, wb2) H2STEP(ACC, ROW, XT, 3, wb3)                \
    H2STEP(ACC, ROW, XT, 4, wb4)

    H2TILE(pa0, rl0, 0)      H2TILE(pa1, rl0, 16)
    H2TILE(pa2, rl0, 32)     H2TILE(pa3, rl0, 48)
    H2TILE(pa4, rl0 + 1, 0)  H2TILE(pa5, rl0 + 1, 16)
    H2TILE(pa6, rl0 + 1, 32) H2TILE(pa7, rl0 + 1, 48)
#undef H2TILE
#undef H2STEP

    const float bb = h2b[0];
    float mg = -1e30f;
#pragma unroll
    for (int r = 0; r < 4; r++) {
      mg = fmaxf(mg, fmaxf(fmaxf(pa0[r], pa1[r]), fmaxf(pa2[r], pa3[r])));
      mg = fmaxf(mg, fmaxf(fmaxf(pa4[r], pa5[r]), fmaxf(pa6[r], pa7[r])));
    }
    mg = (mg + bb) * TEMPF;
    mg = fmaxf(mg, __shfl_xor(mg, 16));
    mg = fmaxf(mg, __shfl_xor(mg, 32));
    float sa = 0.f, sb = 0.f, sx = 0.f;
    const float fq = (float)(qd * 4);
#pragma unroll
    for (int r = 0; r < 4; r++) {
      float xr = fq + (float)r;
      float e;
      e = __expf((pa0[r] + bb) * TEMPF - mg); sa += e; sx += e * (xr + 0.f);
      e = __expf((pa1[r] + bb) * TEMPF - mg); sa += e; sx += e * (xr + 16.f);
      e = __expf((pa2[r] + bb) * TEMPF - mg); sa += e; sx += e * (xr + 32.f);
      e = __expf((pa3[r] + bb) * TEMPF - mg); sa += e; sx += e * (xr + 48.f);
      e = __expf((pa4[r] + bb) * TEMPF - mg); sb += e; sx += e * (xr + 0.f);
      e = __expf((pa5[r] + bb) * TEMPF - mg); sb += e; sx += e * (xr + 16.f);
      e = __expf((pa6[r] + bb) * TEMPF - mg); sb += e; sx += e * (xr + 32.f);
      e = __expf((pa7[r] + bb) * TEMPF - mg); sb += e; sx += e * (xr + 48.f);
    }
    float ya = (float)(y0 + rl0);
    float s = sa + sb;
    float sy = ya * sa + (ya + 1.f) * sb;
    s += __shfl_xor(s, 16); sx += __shfl_xor(sx, 16); sy += __shfl_xor(sy, 16);
    s += __shfl_xor(s, 32); sx += __shfl_xor(sx, 32); sy += __shfl_xor(sy, 32);
    if (lane == 0) {
      int slot = q * 32 + st * 2 + ((role == 3) ? 1 : 0);
      *(float4*)&ws[WS_PART + slot * 4] = make_float4(mg, s, sx, sy);
    }
  }
}

// ---------------------------------------------------------------------------
__device__ __forceinline__ float gelu_tanh(float x) {
  float z = 0.7978845608028654f * (x + 0.044715f * x * x * x);
  z = fminf(fmaxf(z, -15.f), 15.f);
  float e = __expf(2.f * z);
  float th = (e - 1.f) / (e + 1.f);
  return 0.5f * x * (1.f + th);
}

// ---------------------------------------------------------------------------
// corr body (round-6 k_corr, parameterized by query n).
// ---------------------------------------------------------------------------
__device__ __forceinline__ void corr_one(
    int n, int t, float* __restrict__ qs, float (*__restrict__ dbuf)[64],
    float* __restrict__ ws) {
  int wv = t >> 6, lane = t & 63;
  int cl = lane & 15, sub = lane >> 4;
  const float* feats = ws + WS_FEATS + n * 384;
  float posx = ws[WS_POS + n * 2 + 0];
  float posy = ws[WS_POS + n * 2 + 1];
  __hip_bfloat16* mi = (__hip_bfloat16*)(ws + WS_MLPIN) + n * KPAD;

  for (int col = t; col < 384; col += 256) qs[col] = feats[col];
  __syncthreads();

  float qh[8], qq[16];
#pragma unroll
  for (int j = 0; j < 8; j++) qh[j] = qs[cl * 8 + j];
#pragma unroll
  for (int j = 0; j < 16; j++) qq[j] = qs[128 + cl * 16 + j];

  const __hip_bfloat16* G0 = (const __hip_bfloat16*)(ws + WS_HG16);
  const __hip_bfloat16* G1 = (const __hip_bfloat16*)(ws + WS_FG16);
  const __hip_bfloat16* G2 = (const __hip_bfloat16*)(ws + WS_AV16);

#pragma unroll
  for (int L = 0; L < 3; L++) {
    const __hip_bfloat16* grid;
    int Hg, Wg;
    float scl;
    if (L == 0)      { grid = G0; Hg = 128; Wg = 128; scl = 0.25f; }
    else if (L == 1) { grid = G1; Hg = 64;  Wg = 64;  scl = 0.125f; }
    else             { grid = G2; Hg = 32;  Wg = 32;  scl = 0.0625f; }
    float cy = posy * scl, cx = posx * scl;
    int iy = (int)floorf(cy), ix = (int)floorf(cx);
#pragma unroll
    for (int g = 0; g < 4; g++) {
      int p = wv * 16 + g * 4 + sub;
      int a = p >> 3, b = p & 7;
      int row = iy + a - 3; row = row < 0 ? 0 : (row > Hg - 1 ? Hg - 1 : row);
      int col = ix + b - 3; col = col < 0 ? 0 : (col > Wg - 1 ? Wg - 1 : col);
      float acc = 0.f;
      if (L == 0) {
        BU8 g0; g0.u = *(const uint4*)(grid + (row * Wg + col) * 128 + cl * 8);
#pragma unroll
        for (int j = 0; j < 8; j++) acc += __bfloat162float(g0.h[j]) * qh[j];
      } else {
        const __hip_bfloat16* gp = grid + (row * Wg + col) * 256 + cl * 16;
        BU8 g0, g1;
        g0.u = *(const uint4*)gp;
        g1.u = *(const uint4*)(gp + 8);
#pragma unroll
        for (int j = 0; j < 8; j++) {
          acc += __bfloat162float(g0.h[j]) * qq[j];
          acc += __bfloat162float(g1.h[j]) * qq[8 + j];
        }
      }
      acc += __shfl_xor(acc, 1);
      acc += __shfl_xor(acc, 2);
      acc += __shfl_xor(acc, 4);
      acc += __shfl_xor(acc, 8);
      if (cl == 0) dbuf[L][p] = acc;
    }
  }
  __syncthreads();

  if (t < 147) {
    int L = t / 49, s = t - L * 49;
    int sa = s / 7, sb = s - sa * 7;
    float scl = (L == 0) ? 0.25f : ((L == 1) ? 0.125f : 0.0625f);
    float cy = posy * scl, cx = posx * scl;
    float wy = cy - floorf(cy), wx = cx - floorf(cx);
    int i00 = sa * 8 + sb;
    float d00 = dbuf[L][i00], d01 = dbuf[L][i00 + 1];
    float d10 = dbuf[L][i00 + 8], d11 = dbuf[L][i00 + 9];
    float corr = (1.f - wy) * (1.f - wx) * d00 + (1.f - wy) * wx * d01 +
                 wy * (1.f - wx) * d10 + wy * wx * d11;
    mi[388 + t] = __float2bfloat16(corr);
  }
}

// ---------------------------------------------------------------------------
// two-level sense-reversing grid barrier. bar[0..15] leaf counters,
// bar[16] root, bar[17] generation. All blocks must be co-resident.
// ---------------------------------------------------------------------------
__device__ __forceinline__ void grid_bar(int* bar, int nb, int b, int t) {
  __syncthreads();
  if (t == 0) {
    __threadfence();
    int leaf = b & 15;
    int leafN = (nb - leaf + 15) >> 4;
    int nleaf = (nb < 16) ? nb : 16;
    int g = __hip_atomic_load(&bar[17], __ATOMIC_ACQUIRE,
                              __HIP_MEMORY_SCOPE_AGENT);
    int v = __hip_atomic_fetch_add(&bar[leaf], 1, __ATOMIC_ACQ_REL,
                                   __HIP_MEMORY_SCOPE_AGENT);
    if (v == leafN - 1) {
      __hip_atomic_store(&bar[leaf], 0, __ATOMIC_RELAXED,
                         __HIP_MEMORY_SCOPE_AGENT);
      int r = __hip_atomic_fetch_add(&bar[16], 1, __ATOMIC_ACQ_REL,
                                     __HIP_MEMORY_SCOPE_AGENT);
      if (r == nleaf - 1) {
        __hip_atomic_store(&bar[16], 0, __ATOMIC_RELAXED,
                           __HIP_MEMORY_SCOPE_AGENT);
        __hip_atomic_fetch_add(&bar[17], 1, __ATOMIC_RELEASE,
                               __HIP_MEMORY_SCOPE_AGENT);
      } else {
        while (__hip_atomic_load(&bar[17], __ATOMIC_ACQUIRE,
                                 __HIP_MEMORY_SCOPE_AGENT) == g) {}
      }
    } else {
      while (__hip_atomic_load(&bar[17], __ATOMIC_ACQUIRE,
                               __HIP_MEMORY_SCOPE_AGENT) == g) {}
    }
    __threadfence();
  }
  __syncthreads();
}

// ---------------------------------------------------------------------------
// persistent refine: nb blocks (co-resident by construction), 256 threads.
// Phases with round-6 work mapping, grid-strided; manual barrier between:
//   merge (256 items) ; 4x { corr (1024) ; mix1 (512) ; mix2 (448) }.
// ---------------------------------------------------------------------------
__global__ __launch_bounds__(256, 2) void k_refine_pers(
    const float* w4, const float* b4, const float* w5, const float* b5,
    const float* bi, const float* bo, float* ws, float* out, int nb) {
  __shared__ float qs[384];
  __shared__ float dbuf[3][64];
  __shared__ float sums_s[4][32];
  __shared__ float o4s[4][16];

  const int b = blockIdx.x;
  const int t = threadIdx.x;
  const int wv = t >> 6, lane = t & 63;
  int* bar = (int*)(ws + WS_BAR);

  // ---- phase 0: merge (round-6 k_merge body) ----
  for (int item = b; item < 256; item += nb) {
    int q = item * 4 + wv;
    float M = -1e30f, S = 0.f, SX = 0.f, SY = 0.f;
    if (lane < 32) {
      float4 pv = *(const float4*)&ws[WS_PART + (q * 32 + lane) * 4];
      M = pv.x; S = pv.y; SX = pv.z; SY = pv.w;
    }
#pragma unroll
    for (int off = 1; off < 64; off <<= 1) {
      float Mo = __shfl_xor(M, off), So = __shfl_xor(S, off);
      float SXo = __shfl_xor(SX, off), SYo = __shfl_xor(SY, off);
      float Mn = fmaxf(M, Mo);
      float c1 = __expf(M - Mn), c2 = __expf(Mo - Mn);
      S = S * c1 + So * c2; SX = SX * c1 + SXo * c2; SY = SY * c1 + SYo * c2;
      M = Mn;
    }
    if (lane == 0) {
      ws[WS_POS + q * 2 + 0] = (SX / S) * 8.0f;
      ws[WS_POS + q * 2 + 1] = (SY / S) * 8.0f;
    }
    int ch = lane & 31, half = lane >> 5;
    float sm = 0.f;
#pragma unroll
    for (int s8 = 0; s8 < 8; s8++)
      sm += ws[WS_SUM3 + (q * 16 + half * 8 + s8) * 32 + ch];
    sm += __shfl_xor(sm, 32);
    if (lane < 32) sums_s[wv][lane] = sm * (1.f / 1024.f);
    __syncthreads();
    if (lane < 16) {
      float a = b4[lane];
#pragma unroll
      for (int i = 0; i < 32; i++) a += sums_s[wv][i] * w4[i * 16 + lane];
      o4s[wv][lane] = fmaxf(a, 0.f);
    }
    __syncthreads();
    if (lane < 2) {
      float r = b5[lane];
#pragma unroll
      for (int j = 0; j < 16; j++) r += o4s[wv][j] * w5[j * 2 + lane];
      __hip_bfloat16* mi = (__hip_bfloat16*)(ws + WS_MLPIN);
      if (lane == 0) { ws[WS_OCC + q] = r;  mi[q * KPAD + 2] = __float2bfloat16(r); }
      else           { ws[WS_EXPD + q] = r; mi[q * KPAD + 3] = __float2bfloat16(r); }
    }
    __syncthreads();
  }
  grid_bar(bar, nb, b, t);

  const unsigned short* WIT = (const unsigned short*)(ws + WS_WIT);
  const unsigned short* WOT = (const unsigned short*)(ws + WS_WOT);
  const int nl = lane & 15, quad = lane >> 4;

  for (int it = 0; it < 4; ++it) {
    // ---- corr phase ----
    for (int item = b; item < 1024; item += nb) {
      corr_one(item, t, qs, dbuf, ws);
      __syncthreads();
    }
    grid_bar(bar, nb, b, t);

    // ---- mix1 phase (round-6 k_mix1 body) ----
    for (int item = b; item < 512; item += nb) {
      const int nt = (item & 7) * 4 + wv;
      const int mt = item >> 3;
      const int m0 = mt * 16, n0 = nt * 16;
      const unsigned short* Abf = (const unsigned short*)(ws + WS_MLPIN);
      const unsigned short* ap = &Abf[(m0 + nl) * KPAD + quad * 8];
      const unsigned short* bp = &WIT[(n0 + nl) * KPAD + quad * 8];
      f32x4 acc = {0.f, 0.f, 0.f, 0.f};
#pragma unroll
      for (int ks = 0; ks < 17; ks++) {
        bf16x8 a = *(const bf16x8*)(ap + ks * 32);
        bf16x8 bb = *(const bf16x8*)(bp + ks * 32);
        acc = __builtin_amdgcn_mfma_f32_16x16x32_bf16(a, bb, acc, 0, 0, 0);
      }
      __hip_bfloat16* Hd = (__hip_bfloat16*)(ws + WS_HIDDEN);
      int nn = n0 + nl;
      float bv = bi[nn];
#pragma unroll
      for (int r = 0; r < 4; r++) {
        int m = m0 + quad * 4 + r;
        Hd[m * HID + nn] = __float2bfloat16(gelu_tanh(acc[r] + bv));
      }
    }
    grid_bar(bar, nb, b, t);

    // ---- mix2 phase (round-6 k_mix2 body) ----
    for (int item = b; item < 448; item += nb) {
      const int nt = (item % 7) * 4 + wv;
      const int mt = item / 7;
      const int m0 = mt * 16, n0 = nt * 16;
      const unsigned short* Abf = (const unsigned short*)(ws + WS_HIDDEN);
      const unsigned short* ap = &Abf[(m0 + nl) * HID + quad * 8];
      const unsigned short* bp = &WOT[(n0 + nl) * HID + quad * 8];
      f32x4 acc = {0.f, 0.f, 0.f, 0.f};
#pragma unroll
      for (int ks = 0; ks < 16; ks++) {
        bf16x8 a = *(const bf16x8*)(ap + ks * 32);
        bf16x8 bb = *(const bf16x8*)(bp + ks * 32);
        acc = __builtin_amdgcn_mfma_f32_16x16x32_bf16(a, bb, acc, 0, 0, 0);
      }
      int col = n0 + nl;
      if (col < DIMV) {
        float bv = bo[col];
        __hip_bfloat16* mib = (__hip_bfloat16*)(ws + WS_MLPIN);
#pragma unroll
        for (int r = 0; r < 4; r++) {
          int m = m0 + quad * 4 + r;
          float rr = acc[r] + bv;
          if (col < 2) {
            float v = ws[WS_POS + m * 2 + col] + rr;
            ws[WS_POS + m * 2 + col] = v;
            out[m * 4 + col] = v;
          } else if (col == 2) {
            float v = ws[WS_OCC + m] + rr;
            ws[WS_OCC + m] = v;
            out[m * 4 + 2] = v;
            mib[m * KPAD + 2] = __float2bfloat16(v);
          } else if (col == 3) {
            float v = ws[WS_EXPD + m] + rr;
            ws[WS_EXPD + m] = v;
            out[m * 4 + 3] = v;
            mib[m * KPAD + 3] = __float2bfloat16(v);
          } else {
            float v = ws[WS_FEATS + m * 384 + (col - 4)] + rr;
            ws[WS_FEATS + m * 384 + (col - 4)] = v;
            mib[m * KPAD + col] = __float2bfloat16(v);
          }
        }
      }
    }
    if (it < 3) grid_bar(bar, nb, b, t);
  }
}

// ---------------------------------------------------------------------------
extern "C" void kernel_launch(void* const* d_in, const int* in_sizes, int n_in,
                              void* d_out, int out_size, void* d_ws, size_t ws_size,
                              hipStream_t stream) {
  const float* fg = (const float*)d_in[0];
  const float* hg = (const float*)d_in[1];
  const float* qf = (const float*)d_in[2];
  const float* hq = (const float*)d_in[3];
  const float* w1 = (const float*)d_in[4];
  const float* b1 = (const float*)d_in[5];
  const float* w2 = (const float*)d_in[6];
  const float* b2 = (const float*)d_in[7];
  const float* w3 = (const float*)d_in[8];
  const float* b3 = (const float*)d_in[9];
  const float* w4 = (const float*)d_in[10];
  const float* b4 = (const float*)d_in[11];
  const float* w5 = (const float*)d_in[12];
  const float* b5 = (const float*)d_in[13];
  const float* wi = (const float*)d_in[14];
  const float* bi = (const float*)d_in[15];
  const float* wo = (const float*)d_in[16];
  const float* bo = (const float*)d_in[17];
  float* ws = (float*)d_ws;
  float* out = (float*)d_out;

  // persistent-grid sizing (host-side queries only; cached across launches)
  static int nb_cached = 0;
  if (nb_cached == 0) {
    hipDeviceProp_t prop;
    if (hipGetDeviceProperties(&prop, 0) != hipSuccess) prop.multiProcessorCount = 256;
    int perCU = 0;
    if (hipOccupancyMaxActiveBlocksPerMultiprocessor(&perCU, k_refine_pers,
                                                     256, 0) != hipSuccess ||
        perCU < 1)
      perCU = 1;
    long total = (long)perCU * prop.multiProcessorCount;
    if (total > 512) total = 512;
    if (total < 1) total = 1;
    nb_cached = (int)total;
  }
  int nb = nb_cached;

  k_prep_cv<<<11742, 256, 0, stream>>>(fg, hg, qf, hq, w3, w2, wi, wo, ws);
  k_head_stripe<<<16384, 256, 0, stream>>>(w1, b1, b2, b3, ws);
  k_refine_pers<<<nb, 256, 0, stream>>>(w4, b4, w5, b5, bi, bo, ws, out, nb);
}

// Round 10
// 579.088 us; speedup vs baseline: 2.1933x; 2.1933x over previous
//
#include <hip/hip_runtime.h>
#include <hip/hip_bf16.h>
#include <math.h>

// ---------------------------------------------------------------------------
// TAPIR forward. State f32; cv + mixer GEMMs + hid2/hid3 convs via bf16 MFMA.
// fg[64,64,256] hg[128,128,128] qf[1024,256] hq[1024,128] -> out[1024,4]
// 3 dispatches: prep+cv, head stripes, persistent refine (manual grid barrier;
// phase bodies identical to the round-6 split kernels, grid-strided).
// ---------------------------------------------------------------------------

#define NQ 1024
#define TEMPF 20.0f
#define DIMV 388
#define INDIM 535
#define KPAD 544
#define HID 512

// workspace layout (float offsets)
#define WS_CVB     0
#define WS_WIT     2097152                    // bf16 [512][544]
#define WS_WOT     2236416                    // bf16 [448][512]
#define WS_FG16    2351104                    // bf16 fg copy (1048576)
#define WS_HG16    2875392                    // bf16 hg copy (2097152)
#define WS_AV16    3923968                    // bf16 fgavg copy (262144)
#define WS_FGAVG   4194304                    // dead region; hosts barrier state
#define WS_BAR     (WS_FGAVG + 1024)          // 576 ints: 16 padded leaves,
                                              // root @512, gen @544 (128B lines)
#define WS_POS     (WS_FGAVG + 262144)
#define WS_OCC     (WS_POS + NQ*2)
#define WS_EXPD    (WS_OCC + NQ)
#define WS_FEATS   (WS_EXPD + NQ)             // f32 [1024][384]
#define WS_MLPIN   (WS_FEATS + NQ*384)        // bf16 mlp_in [1024][544]
#define WS_HIDDEN  (WS_MLPIN + NQ*KPAD)       // bf16 hidden [1024][512] / SUM3
#define WS_W3B     (WS_HIDDEN + NQ*HID)       // bf16 hid3 B-fragments (5120)
#define WS_W2B     (WS_W3B + 2560)            // bf16 hid2 B-fragments (2560)
#define WS_PART    (WS_MLPIN + 278528)        // softmax partials overlay
#define WS_SUM3    WS_HIDDEN                  // hid3 relu-sums overlay

#define CVP 68                                // cvs LDS pitch
#define ROWP 2368                             // occ_t row pitch bytes

typedef __attribute__((ext_vector_type(8))) short bf16x8;
typedef __attribute__((ext_vector_type(4))) float f32x4;

union BU8 { uint4 u; __hip_bfloat16 h[8]; };

__device__ __forceinline__ int occ_off(int r, int idx, int c) {
  int o = idx * 32 + c * 2;
  o ^= ((idx >> 2) & 3) << 4;
  return r * ROWP + o;
}

// ---------------------------------------------------------------------------
// fused prep + cost volume + all bf16 conversions (round-6 body + barrier
// state zeroing).
// ---------------------------------------------------------------------------
__global__ __launch_bounds__(256) void k_prep_cv(
    const float* __restrict__ fg, const float* __restrict__ hg,
    const float* __restrict__ qf, const float* __restrict__ hq,
    const float* __restrict__ w3, const float* __restrict__ w2,
    const float* __restrict__ wi, const float* __restrict__ wo,
    float* __restrict__ ws) {
  __shared__ __hip_bfloat16 A_s[32 * 32];
  __shared__ __hip_bfloat16 B_s[64 * 32];
  const int bx = blockIdx.x;
  const int t = threadIdx.x;

  if (bx >= 2048) {
    int i = (bx - 2048) * 256 + t;
    if (i < 1024) ((int*)(ws + WS_BAR))[i] = 0;   // grid-barrier state
    if (i < 262144) {
      int c = i & 255, ox = (i >> 8) & 31, oy = i >> 13;
      const float* b = fg + (((oy * 2) * 64 + ox * 2) << 8) + c;
      float av = 0.25f * (b[0] + b[256] + b[16384] + b[16384 + 256]);
      ((__hip_bfloat16*)(ws + WS_AV16))[i] = __float2bfloat16(av);
    } else if (i < 655360) {
      int j = i - 262144;
      int n = j / 384, c = j - n * 384;
      float v = (c < 128) ? hq[n * 128 + c] : qf[n * 256 + c - 128];
      ws[WS_FEATS + j] = v;
      __hip_bfloat16* mi = (__hip_bfloat16*)(ws + WS_MLPIN);
      mi[n * KPAD + 4 + c] = __float2bfloat16(v);
      if (c == 0) {
        mi[n * KPAD + 0] = __float2bfloat16(0.f);
        mi[n * KPAD + 1] = __float2bfloat16(0.f);
      }
    } else if (i < 660480) {
      int j = i - 655360;
      int e = j & 7, qd = (j >> 3) & 3, nl = (j >> 5) & 15;
      int nt = (j >> 9) & 1, kt = j >> 10;
      int k = kt * 32 + qd * 8 + e;
      int ic = k & 15, tap = k >> 4;
      int oc = nt * 16 + nl;
      float v = (tap < 9) ? w3[(oc * 16 + ic) * 9 + tap] : 0.f;
      ((__hip_bfloat16*)(ws + WS_W3B))[j] = __float2bfloat16(v);
    } else if (i < 663040) {
      int j = i - 660480;
      int e = j & 7, qd = (j >> 3) & 3, kt = j >> 9;
      int k = kt * 32 + qd * 8 + e;
      int ch = k & 15, tap = k >> 4;
      float v = (tap < 9) ? w2[ch * 9 + tap] : 0.f;
      ((__hip_bfloat16*)(ws + WS_W2B))[j] = __float2bfloat16(v);
    } else if (i < 1187328) {
      ws[WS_SUM3 + (i - 663040)] = 0.f;
    } else if (i < 1465856) {
      int j = i - 1187328;
      int n = j / KPAD, k = j - n * KPAD;
      float v = (k < INDIM) ? wi[k * HID + n] : 0.f;
      ((__hip_bfloat16*)(ws + WS_WIT))[j] = __float2bfloat16(v);
    } else if (i < 1695232) {
      int j = i - 1465856;
      int n = j >> 9, k = j & 511;
      float v = (n < DIMV) ? wo[k * DIMV + n] : 0.f;
      ((__hip_bfloat16*)(ws + WS_WOT))[j] = __float2bfloat16(v);
    } else if (i < 1957376) {
      int j = (i - 1695232) * 4;
      float4 v = *(const float4*)&fg[j];
      union { __hip_bfloat16 h[4]; uint2 u; } pk;
      pk.h[0] = __float2bfloat16(v.x); pk.h[1] = __float2bfloat16(v.y);
      pk.h[2] = __float2bfloat16(v.z); pk.h[3] = __float2bfloat16(v.w);
      *(uint2*)(((__hip_bfloat16*)(ws + WS_FG16)) + j) = pk.u;
    } else {
      int j = (i - 1957376) * 4;
      float4 v = *(const float4*)&hg[j];
      union { __hip_bfloat16 h[4]; uint2 u; } pk;
      pk.h[0] = __float2bfloat16(v.x); pk.h[1] = __float2bfloat16(v.y);
      pk.h[2] = __float2bfloat16(v.z); pk.h[3] = __float2bfloat16(v.w);
      *(uint2*)(((__hip_bfloat16*)(ws + WS_HG16)) + j) = pk.u;
    }
    return;
  }

  // ---- cv part ----
  const int wv = t >> 6, lane = t & 63;
  const int wm = wv & 1, wn = wv >> 1;
  const int quad = lane >> 4, nl = lane & 15;
  const int p0 = (bx & 63) * 64, m0 = (bx >> 6) * 32;
  f32x4 acc0 = {0.f, 0.f, 0.f, 0.f};
  f32x4 acc1 = {0.f, 0.f, 0.f, 0.f};

  for (int k0 = 0; k0 < 256; k0 += 32) {
    {
      int r = t >> 3, c = t & 7;
      float4 v = *(const float4*)&qf[(m0 + r) * 256 + k0 + c * 4];
      union { __hip_bfloat16 h[4]; uint2 u; } pk;
      pk.h[0] = __float2bfloat16(v.x); pk.h[1] = __float2bfloat16(v.y);
      pk.h[2] = __float2bfloat16(v.z); pk.h[3] = __float2bfloat16(v.w);
      *(uint2*)&A_s[r * 32 + c * 4] = pk.u;
    }
    {
      int r = t >> 2, c = t & 3;
      const float* src = &fg[(p0 + r) * 256 + k0 + c * 8];
      float4 v0 = *(const float4*)src;
      float4 v1 = *(const float4*)(src + 4);
      union { __hip_bfloat16 h[8]; uint4 u; } pk;
      pk.h[0] = __float2bfloat16(v0.x); pk.h[1] = __float2bfloat16(v0.y);
      pk.h[2] = __float2bfloat16(v0.z); pk.h[3] = __float2bfloat16(v0.w);
      pk.h[4] = __float2bfloat16(v1.x); pk.h[5] = __float2bfloat16(v1.y);
      pk.h[6] = __float2bfloat16(v1.z); pk.h[7] = __float2bfloat16(v1.w);
      *(uint4*)&B_s[r * 32 + c * 8] = pk.u;
    }
    __syncthreads();
    bf16x8 a = *(const bf16x8*)&A_s[(16 * wm + nl) * 32 + quad * 8];
    bf16x8 b0 = *(const bf16x8*)&B_s[(32 * wn + nl) * 32 + quad * 8];
    bf16x8 b1 = *(const bf16x8*)&B_s[(32 * wn + 16 + nl) * 32 + quad * 8];
    acc0 = __builtin_amdgcn_mfma_f32_16x16x32_bf16(a, b0, acc0, 0, 0, 0);
    acc1 = __builtin_amdgcn_mfma_f32_16x16x32_bf16(a, b1, acc1, 0, 0, 0);
    __syncthreads();
  }
  __hip_bfloat16* cvb = (__hip_bfloat16*)ws;
#pragma unroll
  for (int nt = 0; nt < 2; nt++) {
    int n = p0 + 32 * wn + nt * 16 + nl;
#pragma unroll
    for (int r = 0; r < 4; r++) {
      int m = m0 + 16 * wm + quad * 4 + r;
      cvb[m * 4096 + n] = __float2bfloat16(nt ? acc1[r] : acc0[r]);
    }
  }
}

// ---------------------------------------------------------------------------
// head stripe kernel (unchanged from round 6): 16384 blocks.
// ---------------------------------------------------------------------------
__global__ __launch_bounds__(256, 5) void k_head_stripe(
    const float* __restrict__ h1w, const float* __restrict__ h1b,
    const float* __restrict__ h2b, const float* __restrict__ h3b,
    float* __restrict__ ws) {
  __shared__ float cvs[8 * CVP];
  __shared__ float4 occ_t4[6 * ROWP / 16];
  char* occ_t = (char*)occ_t4;

  const int bx = blockIdx.x;
  const int q = bx >> 4, st = bx & 15;
  const int y0 = st * 4;
  const int t = threadIdx.x;
  const int wv = t >> 6, lane = t & 63;
  const int role = (wv + bx) & 3;
  const __hip_bfloat16* cvb = (const __hip_bfloat16*)ws + q * 4096;

  if (t < 192) {
    int r = t >> 5, j = t & 31;
    int off = r * ROWP + ((j < 16) ? j * 8 : 2176 + (j - 16) * 8);
    *(uint2*)(occ_t + off) = make_uint2(0u, 0u);
  }
  if (st == 0 || st == 15) {
    int r = (st == 0) ? 0 : 5;
    for (int i = t; i < 288; i += 256)
      *(uint2*)(occ_t + r * ROWP + i * 8) = make_uint2(0u, 0u);
  }
#pragma unroll
  for (int j = 0; j < 2; j++) {
    int i = t + 256 * j;
    int lr = i >> 6, x = i & 63;
    int g = y0 - 2 + lr;
    cvs[lr * CVP + x + 1] =
        (g >= 0 && g < 64) ? __bfloat162float(cvb[g * 64 + x]) : 0.f;
  }
  if (t < 32) {
    int rr = t >> 2, c = t & 3;
    cvs[rr * CVP + ((c == 0) ? 0 : (64 + c))] = 0.f;
  }
  __syncthreads();

  {
    const int x = lane;
    const int chg = wv * 4;
    float w1r[4][9], b1r[4];
#pragma unroll
    for (int k = 0; k < 4; k++) {
      b1r[k] = h1b[chg + k];
#pragma unroll
      for (int j = 0; j < 9; j++) w1r[k][j] = h1w[(chg + k) * 9 + j];
    }
    float win[3][3];
#pragma unroll
    for (int j = 0; j < 3; j++) {
      const float* cp = &cvs[j * CVP + x];
      win[j][0] = cp[0]; win[j][1] = cp[1]; win[j][2] = cp[2];
    }
    for (int r = 0; r < 6; r++) {
      if (r > 0) {
#pragma unroll
        for (int c = 0; c < 3; c++) { win[0][c] = win[1][c]; win[1][c] = win[2][c]; }
        const float* cp = &cvs[(r + 2) * CVP + x];
        win[2][0] = cp[0]; win[2][1] = cp[1]; win[2][2] = cp[2];
      }
      int yo = y0 - 1 + r;
      if (yo >= 0 && yo <= 63) {
        union { __hip_bfloat16 h[4]; uint2 u; } pk;
#pragma unroll
        for (int k = 0; k < 4; k++) {
          float a = b1r[k];
#pragma unroll
          for (int ky = 0; ky < 3; ky++)
            a += w1r[k][3 * ky] * win[ky][0] + w1r[k][3 * ky + 1] * win[ky][1] +
                 w1r[k][3 * ky + 2] * win[ky][2];
          pk.h[k] = __float2bfloat16(fmaxf(a, 0.f));
        }
        *(uint2*)(occ_t + occ_off(r, x + 4, chg)) = pk.u;
      }
    }
  }
  __syncthreads();

  const int nl = lane & 15;
  const int qd = lane >> 4, qh = qd >> 1, ql = qd & 1;

  if (role == 1 || role == 2) {
    const __hip_bfloat16* W3B = (const __hip_bfloat16*)(ws + WS_W3B);
    const int oyl = role - 1;
    f32x4 acc00 = {0.f,0.f,0.f,0.f}, acc01 = {0.f,0.f,0.f,0.f};
    f32x4 acc10 = {0.f,0.f,0.f,0.f}, acc11 = {0.f,0.f,0.f,0.f};
#pragma unroll
    for (int kt = 0; kt < 5; kt++) {
      int tap = kt * 2 + qh;
      bf16x8 a0, a1;
      if (tap < 9) {
        int ky = (tap >= 6) ? 2 : ((tap >= 3) ? 1 : 0);
        int kx = tap - 3 * ky;
        int R = 2 * oyl + 1 + ky;
        int idx0 = 4 + kx + 2 * nl;
        a0 = *(const bf16x8*)(occ_t + occ_off(R, idx0, ql * 8));
        a1 = *(const bf16x8*)(occ_t + occ_off(R, idx0 + 32, ql * 8));
      } else {
        a0 = (bf16x8){0, 0, 0, 0, 0, 0, 0, 0};
        a1 = a0;
      }
      bf16x8 b0 = *(const bf16x8*)&W3B[((kt * 2 + 0) * 16 + nl) * 32 + qd * 8];
      bf16x8 b1 = *(const bf16x8*)&W3B[((kt * 2 + 1) * 16 + nl) * 32 + qd * 8];
      acc00 = __builtin_amdgcn_mfma_f32_16x16x32_bf16(a0, b0, acc00, 0, 0, 0);
      acc01 = __builtin_amdgcn_mfma_f32_16x16x32_bf16(a0, b1, acc01, 0, 0, 0);
      acc10 = __builtin_amdgcn_mfma_f32_16x16x32_bf16(a1, b0, acc10, 0, 0, 0);
      acc11 = __builtin_amdgcn_mfma_f32_16x16x32_bf16(a1, b1, acc11, 0, 0, 0);
    }
    float bb0 = h3b[nl], bb1 = h3b[16 + nl];
    float s0 = 0.f, s1 = 0.f;
#pragma unroll
    for (int r = 0; r < 4; r++) {
      s0 += fmaxf(acc00[r] + bb0, 0.f) + fmaxf(acc10[r] + bb0, 0.f);
      s1 += fmaxf(acc01[r] + bb1, 0.f) + fmaxf(acc11[r] + bb1, 0.f);
    }
    s0 += __shfl_xor(s0, 16); s0 += __shfl_xor(s0, 32);
    s1 += __shfl_xor(s1, 16); s1 += __shfl_xor(s1, 32);
    if (lane < 16) {
      atomicAdd(&ws[WS_SUM3 + (q * 16 + st) * 32 + nl], s0);
      atomicAdd(&ws[WS_SUM3 + (q * 16 + st) * 32 + 16 + nl], s1);
    }
  } else {
    const int rl0 = (role == 3) ? 2 : 0;
    const __hip_bfloat16* W2B = (const __hip_bfloat16*)(ws + WS_W2B);
    bf16x8 wb0 = *(const bf16x8*)&W2B[(0 * 16 + nl) * 32 + qd * 8];
    bf16x8 wb1 = *(const bf16x8*)&W2B[(1 * 16 + nl) * 32 + qd * 8];
    bf16x8 wb2 = *(const bf16x8*)&W2B[(2 * 16 + nl) * 32 + qd * 8];
    bf16x8 wb3 = *(const bf16x8*)&W2B[(3 * 16 + nl) * 32 + qd * 8];
    bf16x8 wb4 = *(const bf16x8*)&W2B[(4 * 16 + nl) * 32 + qd * 8];
    f32x4 pa0 = {0.f,0.f,0.f,0.f}, pa1 = {0.f,0.f,0.f,0.f};
    f32x4 pa2 = {0.f,0.f,0.f,0.f}, pa3 = {0.f,0.f,0.f,0.f};
    f32x4 pa4 = {0.f,0.f,0.f,0.f}, pa5 = {0.f,0.f,0.f,0.f};
    f32x4 pa6 = {0.f,0.f,0.f,0.f}, pa7 = {0.f,0.f,0.f,0.f};

#define H2STEP(ACC, ROW, XT, KT, WB)                                         \
    {                                                                        \
      int tap = (KT) * 2 + qh;                                               \
      bf16x8 a;                                                              \
      if (tap < 9) {                                                         \
        int ky = (tap >= 6) ? 2 : ((tap >= 3) ? 1 : 0);                      \
        int kx = tap - 3 * ky;                                               \
        a = *(const bf16x8*)(occ_t +                                         \
            occ_off((ROW) + ky, (XT) + nl + 3 + kx, ql * 8));                \
      } else { a = (bf16x8){0, 0, 0, 0, 0, 0, 0, 0}; }                       \
      ACC = __builtin_amdgcn_mfma_f32_16x16x32_bf16(a, WB, ACC, 0, 0, 0);    \
    }
#define H2TILE(ACC, ROW, XT)                                                 \
    H2STEP(ACC, ROW, XT, 0, wb0) H2STEP(ACC, ROW, XT, 1, wb1)                \
    H2STEP(ACC, ROW, XT, 2, wb2) H2STEP(ACC, ROW, XT, 3, wb3)                \
    H2STEP(ACC, ROW, XT, 4, wb4)

    H2TILE(pa0, rl0, 0)      H2TILE(pa1, rl0, 16)
    H2TILE(pa2, rl0, 32)     H2TILE(pa3, rl0, 48)
    H2TILE(pa4, rl0 + 1, 0)  H2TILE(pa5, rl0 + 1, 16)
    H2TILE(pa6, rl0 + 1, 32) H2TILE(pa7, rl0 + 1, 48)
#undef H2TILE
#undef H2STEP

    const float bb = h2b[0];
    float mg = -1e30f;
#pragma unroll
    for (int r = 0; r < 4; r++) {
      mg = fmaxf(mg, fmaxf(fmaxf(pa0[r], pa1[r]), fmaxf(pa2[r], pa3[r])));
      mg = fmaxf(mg, fmaxf(fmaxf(pa4[r], pa5[r]), fmaxf(pa6[r], pa7[r])));
    }
    mg = (mg + bb) * TEMPF;
    mg = fmaxf(mg, __shfl_xor(mg, 16));
    mg = fmaxf(mg, __shfl_xor(mg, 32));
    float sa = 0.f, sb = 0.f, sx = 0.f;
    const float fq = (float)(qd * 4);
#pragma unroll
    for (int r = 0; r < 4; r++) {
      float xr = fq + (float)r;
      float e;
      e = __expf((pa0[r] + bb) * TEMPF - mg); sa += e; sx += e * (xr + 0.f);
      e = __expf((pa1[r] + bb) * TEMPF - mg); sa += e; sx += e * (xr + 16.f);
      e = __expf((pa2[r] + bb) * TEMPF - mg); sa += e; sx += e * (xr + 32.f);
      e = __expf((pa3[r] + bb) * TEMPF - mg); sa += e; sx += e * (xr + 48.f);
      e = __expf((pa4[r] + bb) * TEMPF - mg); sb += e; sx += e * (xr + 0.f);
      e = __expf((pa5[r] + bb) * TEMPF - mg); sb += e; sx += e * (xr + 16.f);
      e = __expf((pa6[r] + bb) * TEMPF - mg); sb += e; sx += e * (xr + 32.f);
      e = __expf((pa7[r] + bb) * TEMPF - mg); sb += e; sx += e * (xr + 48.f);
    }
    float ya = (float)(y0 + rl0);
    float s = sa + sb;
    float sy = ya * sa + (ya + 1.f) * sb;
    s += __shfl_xor(s, 16); sx += __shfl_xor(sx, 16); sy += __shfl_xor(sy, 16);
    s += __shfl_xor(s, 32); sx += __shfl_xor(sx, 32); sy += __shfl_xor(sy, 32);
    if (lane == 0) {
      int slot = q * 32 + st * 2 + ((role == 3) ? 1 : 0);
      *(float4*)&ws[WS_PART + slot * 4] = make_float4(mg, s, sx, sy);
    }
  }
}

// ---------------------------------------------------------------------------
__device__ __forceinline__ float gelu_tanh(float x) {
  float z = 0.7978845608028654f * (x + 0.044715f * x * x * x);
  z = fminf(fmaxf(z, -15.f), 15.f);
  float e = __expf(2.f * z);
  float th = (e - 1.f) / (e + 1.f);
  return 0.5f * x * (1.f + th);
}

// ---------------------------------------------------------------------------
// corr body (round-6 k_corr, parameterized by query n).
// ---------------------------------------------------------------------------
__device__ __forceinline__ void corr_one(
    int n, int t, float* __restrict__ qs, float (*__restrict__ dbuf)[64],
    float* __restrict__ ws) {
  int wv = t >> 6, lane = t & 63;
  int cl = lane & 15, sub = lane >> 4;
  const float* feats = ws + WS_FEATS + n * 384;
  float posx = ws[WS_POS + n * 2 + 0];
  float posy = ws[WS_POS + n * 2 + 1];
  __hip_bfloat16* mi = (__hip_bfloat16*)(ws + WS_MLPIN) + n * KPAD;

  for (int col = t; col < 384; col += 256) qs[col] = feats[col];
  __syncthreads();

  float qh[8], qq[16];
#pragma unroll
  for (int j = 0; j < 8; j++) qh[j] = qs[cl * 8 + j];
#pragma unroll
  for (int j = 0; j < 16; j++) qq[j] = qs[128 + cl * 16 + j];

  const __hip_bfloat16* G0 = (const __hip_bfloat16*)(ws + WS_HG16);
  const __hip_bfloat16* G1 = (const __hip_bfloat16*)(ws + WS_FG16);
  const __hip_bfloat16* G2 = (const __hip_bfloat16*)(ws + WS_AV16);

#pragma unroll
  for (int L = 0; L < 3; L++) {
    const __hip_bfloat16* grid;
    int Hg, Wg;
    float scl;
    if (L == 0)      { grid = G0; Hg = 128; Wg = 128; scl = 0.25f; }
    else if (L == 1) { grid = G1; Hg = 64;  Wg = 64;  scl = 0.125f; }
    else             { grid = G2; Hg = 32;  Wg = 32;  scl = 0.0625f; }
    float cy = posy * scl, cx = posx * scl;
    int iy = (int)floorf(cy), ix = (int)floorf(cx);
#pragma unroll
    for (int g = 0; g < 4; g++) {
      int p = wv * 16 + g * 4 + sub;
      int a = p >> 3, b = p & 7;
      int row = iy + a - 3; row = row < 0 ? 0 : (row > Hg - 1 ? Hg - 1 : row);
      int col = ix + b - 3; col = col < 0 ? 0 : (col > Wg - 1 ? Wg - 1 : col);
      float acc = 0.f;
      if (L == 0) {
        BU8 g0; g0.u = *(const uint4*)(grid + (row * Wg + col) * 128 + cl * 8);
#pragma unroll
        for (int j = 0; j < 8; j++) acc += __bfloat162float(g0.h[j]) * qh[j];
      } else {
        const __hip_bfloat16* gp = grid + (row * Wg + col) * 256 + cl * 16;
        BU8 g0, g1;
        g0.u = *(const uint4*)gp;
        g1.u = *(const uint4*)(gp + 8);
#pragma unroll
        for (int j = 0; j < 8; j++) {
          acc += __bfloat162float(g0.h[j]) * qq[j];
          acc += __bfloat162float(g1.h[j]) * qq[8 + j];
        }
      }
      acc += __shfl_xor(acc, 1);
      acc += __shfl_xor(acc, 2);
      acc += __shfl_xor(acc, 4);
      acc += __shfl_xor(acc, 8);
      if (cl == 0) dbuf[L][p] = acc;
    }
  }
  __syncthreads();

  if (t < 147) {
    int L = t / 49, s = t - L * 49;
    int sa = s / 7, sb = s - sa * 7;
    float scl = (L == 0) ? 0.25f : ((L == 1) ? 0.125f : 0.0625f);
    float cy = posy * scl, cx = posx * scl;
    float wy = cy - floorf(cy), wx = cx - floorf(cx);
    int i00 = sa * 8 + sb;
    float d00 = dbuf[L][i00], d01 = dbuf[L][i00 + 1];
    float d10 = dbuf[L][i00 + 8], d11 = dbuf[L][i00 + 9];
    float corr = (1.f - wy) * (1.f - wx) * d00 + (1.f - wy) * wx * d01 +
                 wy * (1.f - wx) * d10 + wy * wx * d11;
    mi[388 + t] = __float2bfloat16(corr);
  }
}

// ---------------------------------------------------------------------------
// two-level sense-reversing grid barrier. Leaf i at bar[i*32] (128B-padded),
// root at bar[512], generation at bar[544]. RELAXED counter RMWs + RELAXED
// polls with s_sleep backoff; ordering via __threadfence() at entry (release)
// and after poll-exit (acquire). All blocks must be co-resident.
// ---------------------------------------------------------------------------
__device__ __forceinline__ void grid_bar(int* bar, int nb, int b, int t) {
  __syncthreads();
  if (t == 0) {
    __threadfence();
    int leaf = b & 15;
    int* leafp = &bar[leaf * 32];
    int* rootp = &bar[512];
    int* genp = &bar[544];
    int leafN = (nb - leaf + 15) >> 4;
    int nleaf = (nb < 16) ? nb : 16;
    int g = __hip_atomic_load(genp, __ATOMIC_RELAXED, __HIP_MEMORY_SCOPE_AGENT);
    int v = __hip_atomic_fetch_add(leafp, 1, __ATOMIC_RELAXED,
                                   __HIP_MEMORY_SCOPE_AGENT);
    if (v == leafN - 1) {
      __hip_atomic_store(leafp, 0, __ATOMIC_RELAXED, __HIP_MEMORY_SCOPE_AGENT);
      int r = __hip_atomic_fetch_add(rootp, 1, __ATOMIC_RELAXED,
                                     __HIP_MEMORY_SCOPE_AGENT);
      if (r == nleaf - 1) {
        __hip_atomic_store(rootp, 0, __ATOMIC_RELAXED,
                           __HIP_MEMORY_SCOPE_AGENT);
        __hip_atomic_fetch_add(genp, 1, __ATOMIC_RELEASE,
                               __HIP_MEMORY_SCOPE_AGENT);
      } else {
        while (__hip_atomic_load(genp, __ATOMIC_RELAXED,
                                 __HIP_MEMORY_SCOPE_AGENT) == g)
          __builtin_amdgcn_s_sleep(8);
      }
    } else {
      while (__hip_atomic_load(genp, __ATOMIC_RELAXED,
                               __HIP_MEMORY_SCOPE_AGENT) == g)
        __builtin_amdgcn_s_sleep(8);
    }
    __threadfence();
  }
  __syncthreads();
}

// ---------------------------------------------------------------------------
// persistent refine: nb blocks (co-resident by construction), 256 threads.
// Phases with round-6 work mapping, grid-strided; manual barrier between:
//   merge (256 items) ; 4x { corr (1024) ; mix1 (512) ; mix2 (448) }.
// ---------------------------------------------------------------------------
__global__ __launch_bounds__(256, 2) void k_refine_pers(
    const float* w4, const float* b4, const float* w5, const float* b5,
    const float* bi, const float* bo, float* ws, float* out, int nb) {
  __shared__ float qs[384];
  __shared__ float dbuf[3][64];
  __shared__ float sums_s[4][32];
  __shared__ float o4s[4][16];

  const int b = blockIdx.x;
  const int t = threadIdx.x;
  const int wv = t >> 6, lane = t & 63;
  int* bar = (int*)(ws + WS_BAR);

  // ---- phase 0: merge (round-6 k_merge body) ----
  for (int item = b; item < 256; item += nb) {
    int q = item * 4 + wv;
    float M = -1e30f, S = 0.f, SX = 0.f, SY = 0.f;
    if (lane < 32) {
      float4 pv = *(const float4*)&ws[WS_PART + (q * 32 + lane) * 4];
      M = pv.x; S = pv.y; SX = pv.z; SY = pv.w;
    }
#pragma unroll
    for (int off = 1; off < 64; off <<= 1) {
      float Mo = __shfl_xor(M, off), So = __shfl_xor(S, off);
      float SXo = __shfl_xor(SX, off), SYo = __shfl_xor(SY, off);
      float Mn = fmaxf(M, Mo);
      float c1 = __expf(M - Mn), c2 = __expf(Mo - Mn);
      S = S * c1 + So * c2; SX = SX * c1 + SXo * c2; SY = SY * c1 + SYo * c2;
      M = Mn;
    }
    if (lane == 0) {
      ws[WS_POS + q * 2 + 0] = (SX / S) * 8.0f;
      ws[WS_POS + q * 2 + 1] = (SY / S) * 8.0f;
    }
    int ch = lane & 31, half = lane >> 5;
    float sm = 0.f;
#pragma unroll
    for (int s8 = 0; s8 < 8; s8++)
      sm += ws[WS_SUM3 + (q * 16 + half * 8 + s8) * 32 + ch];
    sm += __shfl_xor(sm, 32);
    if (lane < 32) sums_s[wv][lane] = sm * (1.f / 1024.f);
    __syncthreads();
    if (lane < 16) {
      float a = b4[lane];
#pragma unroll
      for (int i = 0; i < 32; i++) a += sums_s[wv][i] * w4[i * 16 + lane];
      o4s[wv][lane] = fmaxf(a, 0.f);
    }
    __syncthreads();
    if (lane < 2) {
      float r = b5[lane];
#pragma unroll
      for (int j = 0; j < 16; j++) r += o4s[wv][j] * w5[j * 2 + lane];
      __hip_bfloat16* mi = (__hip_bfloat16*)(ws + WS_MLPIN);
      if (lane == 0) { ws[WS_OCC + q] = r;  mi[q * KPAD + 2] = __float2bfloat16(r); }
      else           { ws[WS_EXPD + q] = r; mi[q * KPAD + 3] = __float2bfloat16(r); }
    }
    __syncthreads();
  }
  grid_bar(bar, nb, b, t);

  const unsigned short* WIT = (const unsigned short*)(ws + WS_WIT);
  const unsigned short* WOT = (const unsigned short*)(ws + WS_WOT);
  const int nl = lane & 15, quad = lane >> 4;

  for (int it = 0; it < 4; ++it) {
    // ---- corr phase ----
    for (int item = b; item < 1024; item += nb) {
      corr_one(item, t, qs, dbuf, ws);
      __syncthreads();
    }
    grid_bar(bar, nb, b, t);

    // ---- mix1 phase (round-6 k_mix1 body) ----
    for (int item = b; item < 512; item += nb) {
      const int nt = (item & 7) * 4 + wv;
      const int mt = item >> 3;
      const int m0 = mt * 16, n0 = nt * 16;
      const unsigned short* Abf = (const unsigned short*)(ws + WS_MLPIN);
      const unsigned short* ap = &Abf[(m0 + nl) * KPAD + quad * 8];
      const unsigned short* bp = &WIT[(n0 + nl) * KPAD + quad * 8];
      f32x4 acc = {0.f, 0.f, 0.f, 0.f};
#pragma unroll
      for (int ks = 0; ks < 17; ks++) {
        bf16x8 a = *(const bf16x8*)(ap + ks * 32);
        bf16x8 bb = *(const bf16x8*)(bp + ks * 32);
        acc = __builtin_amdgcn_mfma_f32_16x16x32_bf16(a, bb, acc, 0, 0, 0);
      }
      __hip_bfloat16* Hd = (__hip_bfloat16*)(ws + WS_HIDDEN);
      int nn = n0 + nl;
      float bv = bi[nn];
#pragma unroll
      for (int r = 0; r < 4; r++) {
        int m = m0 + quad * 4 + r;
        Hd[m * HID + nn] = __float2bfloat16(gelu_tanh(acc[r] + bv));
      }
    }
    grid_bar(bar, nb, b, t);

    // ---- mix2 phase (round-6 k_mix2 body) ----
    for (int item = b; item < 448; item += nb) {
      const int nt = (item % 7) * 4 + wv;
      const int mt = item / 7;
      const int m0 = mt * 16, n0 = nt * 16;
      const unsigned short* Abf = (const unsigned short*)(ws + WS_HIDDEN);
      const unsigned short* ap = &Abf[(m0 + nl) * HID + quad * 8];
      const unsigned short* bp = &WOT[(n0 + nl) * HID + quad * 8];
      f32x4 acc = {0.f, 0.f, 0.f, 0.f};
#pragma unroll
      for (int ks = 0; ks < 16; ks++) {
        bf16x8 a = *(const bf16x8*)(ap + ks * 32);
        bf16x8 bb = *(const bf16x8*)(bp + ks * 32);
        acc = __builtin_amdgcn_mfma_f32_16x16x32_bf16(a, bb, acc, 0, 0, 0);
      }
      int col = n0 + nl;
      if (col < DIMV) {
        float bv = bo[col];
        __hip_bfloat16* mib = (__hip_bfloat16*)(ws + WS_MLPIN);
#pragma unroll
        for (int r = 0; r < 4; r++) {
          int m = m0 + quad * 4 + r;
          float rr = acc[r] + bv;
          if (col < 2) {
            float v = ws[WS_POS + m * 2 + col] + rr;
            ws[WS_POS + m * 2 + col] = v;
            out[m * 4 + col] = v;
          } else if (col == 2) {
            float v = ws[WS_OCC + m] + rr;
            ws[WS_OCC + m] = v;
            out[m * 4 + 2] = v;
            mib[m * KPAD + 2] = __float2bfloat16(v);
          } else if (col == 3) {
            float v = ws[WS_EXPD + m] + rr;
            ws[WS_EXPD + m] = v;
            out[m * 4 + 3] = v;
            mib[m * KPAD + 3] = __float2bfloat16(v);
          } else {
            float v = ws[WS_FEATS + m * 384 + (col - 4)] + rr;
            ws[WS_FEATS + m * 384 + (col - 4)] = v;
            mib[m * KPAD + col] = __float2bfloat16(v);
          }
        }
      }
    }
    if (it < 3) grid_bar(bar, nb, b, t);
  }
}

// ---------------------------------------------------------------------------
extern "C" void kernel_launch(void* const* d_in, const int* in_sizes, int n_in,
                              void* d_out, int out_size, void* d_ws, size_t ws_size,
                              hipStream_t stream) {
  const float* fg = (const float*)d_in[0];
  const float* hg = (const float*)d_in[1];
  const float* qf = (const float*)d_in[2];
  const float* hq = (const float*)d_in[3];
  const float* w1 = (const float*)d_in[4];
  const float* b1 = (const float*)d_in[5];
  const float* w2 = (const float*)d_in[6];
  const float* b2 = (const float*)d_in[7];
  const float* w3 = (const float*)d_in[8];
  const float* b3 = (const float*)d_in[9];
  const float* w4 = (const float*)d_in[10];
  const float* b4 = (const float*)d_in[11];
  const float* w5 = (const float*)d_in[12];
  const float* b5 = (const float*)d_in[13];
  const float* wi = (const float*)d_in[14];
  const float* bi = (const float*)d_in[15];
  const float* wo = (const float*)d_in[16];
  const float* bo = (const float*)d_in[17];
  float* ws = (float*)d_ws;
  float* out = (float*)d_out;

  // persistent-grid sizing (host-side queries only; cached across launches)
  static int nb_cached = 0;
  if (nb_cached == 0) {
    hipDeviceProp_t prop;
    if (hipGetDeviceProperties(&prop, 0) != hipSuccess) prop.multiProcessorCount = 256;
    int perCU = 0;
    if (hipOccupancyMaxActiveBlocksPerMultiprocessor(&perCU, k_refine_pers,
                                                     256, 0) != hipSuccess ||
        perCU < 1)
      perCU = 1;
    long total = (long)perCU * prop.multiProcessorCount;
    if (total > 512) total = 512;
    if (total < 1) total = 1;
    nb_cached = (int)total;
  }
  int nb = nb_cached;

  k_prep_cv<<<11742, 256, 0, stream>>>(fg, hg, qf, hq, w3, w2, wi, wo, ws);
  k_head_stripe<<<16384, 256, 0, stream>>>(w1, b1, b2, b3, ws);
  k_refine_pers<<<nb, 256, 0, stream>>>(w4, b4, w5, b5, bi, bo, ws, out, nb);
}

// Round 11
// 298.033 us; speedup vs baseline: 4.2616x; 1.9430x over previous
//
#include <hip/hip_runtime.h>
#include <hip/hip_bf16.h>
#include <math.h>

// ---------------------------------------------------------------------------
// TAPIR forward. State f32; cv + mixer GEMMs + hid2/hid3 convs via bf16 MFMA.
// fg[64,64,256] hg[128,128,128] qf[1024,256] hq[1024,128] -> out[1024,4]
// Round-6 configuration (session optimum): prep+cv, head stripes, merge,
// 4x (corr, mix1, mix2) as plain dispatches.
// ---------------------------------------------------------------------------

#define NQ 1024
#define TEMPF 20.0f
#define DIMV 388
#define INDIM 535
#define KPAD 544
#define HID 512

// workspace layout (float offsets)
#define WS_CVB     0
#define WS_WIT     2097152                    // bf16 [512][544]
#define WS_WOT     2236416                    // bf16 [448][512]
#define WS_FG16    2351104                    // bf16 fg copy (1048576)
#define WS_HG16    2875392                    // bf16 hg copy (2097152)
#define WS_AV16    3923968                    // bf16 fgavg copy (262144)
#define WS_FGAVG   4194304                    // (unused; kept for layout)
#define WS_POS     (WS_FGAVG + 262144)
#define WS_OCC     (WS_POS + NQ*2)
#define WS_EXPD    (WS_OCC + NQ)
#define WS_FEATS   (WS_EXPD + NQ)             // f32 [1024][384]
#define WS_MLPIN   (WS_FEATS + NQ*384)        // bf16 mlp_in [1024][544]
#define WS_HIDDEN  (WS_MLPIN + NQ*KPAD)       // bf16 hidden [1024][512] / SUM3
#define WS_W3B     (WS_HIDDEN + NQ*HID)       // bf16 hid3 B-fragments (5120)
#define WS_W2B     (WS_W3B + 2560)            // bf16 hid2 B-fragments (2560)
#define WS_PART    (WS_MLPIN + 278528)        // softmax partials overlay
#define WS_SUM3    WS_HIDDEN                  // hid3 relu-sums overlay

#define CVP 68                                // cvs LDS pitch
#define ROWP 2368                             // occ_t row pitch bytes

typedef __attribute__((ext_vector_type(8))) short bf16x8;
typedef __attribute__((ext_vector_type(4))) float f32x4;

union BU8 { uint4 u; __hip_bfloat16 h[8]; };

// swizzled byte offset into occ_t: row r (0..5), x-index idx (0..71, = x+4),
// channel c (0..15). XOR of byte bits 4-5 with idx bits 2-3 spreads the
// x-stride-32B MFMA fragment reads across LDS banks. 16B alignment preserved.
__device__ __forceinline__ int occ_off(int r, int idx, int c) {
  int o = idx * 32 + c * 2;
  o ^= ((idx >> 2) & 3) << 4;
  return r * ROWP + o;
}

// ---------------------------------------------------------------------------
// fused prep + cost volume + all bf16 conversions.
// blocks 0..2047: cv (bf16 MFMA) -> bf16 store.
// blocks 2048..: AV16, feats/mlp_in init, W3B/W2B pack, SUM3 zero,
//                WIT/WOT transpose-convert, FG16/HG16 vectorized convert.
// ---------------------------------------------------------------------------
__global__ __launch_bounds__(256) void k_prep_cv(
    const float* __restrict__ fg, const float* __restrict__ hg,
    const float* __restrict__ qf, const float* __restrict__ hq,
    const float* __restrict__ w3, const float* __restrict__ w2,
    const float* __restrict__ wi, const float* __restrict__ wo,
    float* __restrict__ ws) {
  __shared__ __hip_bfloat16 A_s[32 * 32];
  __shared__ __hip_bfloat16 B_s[64 * 32];
  const int bx = blockIdx.x;
  const int t = threadIdx.x;

  if (bx >= 2048) {
    int i = (bx - 2048) * 256 + t;
    if (i < 262144) {
      // fg 2x2 average -> AV16 bf16 directly
      int c = i & 255, ox = (i >> 8) & 31, oy = i >> 13;
      const float* b = fg + (((oy * 2) * 64 + ox * 2) << 8) + c;
      float av = 0.25f * (b[0] + b[256] + b[16384] + b[16384 + 256]);
      ((__hip_bfloat16*)(ws + WS_AV16))[i] = __float2bfloat16(av);
    } else if (i < 655360) {
      int j = i - 262144;
      int n = j / 384, c = j - n * 384;
      float v = (c < 128) ? hq[n * 128 + c] : qf[n * 256 + c - 128];
      ws[WS_FEATS + j] = v;
      __hip_bfloat16* mi = (__hip_bfloat16*)(ws + WS_MLPIN);
      mi[n * KPAD + 4 + c] = __float2bfloat16(v);
      if (c == 0) {
        mi[n * KPAD + 0] = __float2bfloat16(0.f);
        mi[n * KPAD + 1] = __float2bfloat16(0.f);
      }
    } else if (i < 660480) {
      int j = i - 655360;                     // W3B: 5120 bf16
      int e = j & 7, qd = (j >> 3) & 3, nl = (j >> 5) & 15;
      int nt = (j >> 9) & 1, kt = j >> 10;
      int k = kt * 32 + qd * 8 + e;
      int ic = k & 15, tap = k >> 4;
      int oc = nt * 16 + nl;
      float v = (tap < 9) ? w3[(oc * 16 + ic) * 9 + tap] : 0.f;
      ((__hip_bfloat16*)(ws + WS_W3B))[j] = __float2bfloat16(v);
    } else if (i < 663040) {
      int j = i - 660480;                     // W2B: 2560 bf16, n-broadcast
      int e = j & 7, qd = (j >> 3) & 3, kt = j >> 9;
      int k = kt * 32 + qd * 8 + e;
      int ch = k & 15, tap = k >> 4;
      float v = (tap < 9) ? w2[ch * 9 + tap] : 0.f;
      ((__hip_bfloat16*)(ws + WS_W2B))[j] = __float2bfloat16(v);
    } else if (i < 1187328) {
      ws[WS_SUM3 + (i - 663040)] = 0.f;
    } else if (i < 1465856) {
      int j = i - 1187328;
      int n = j / KPAD, k = j - n * KPAD;
      float v = (k < INDIM) ? wi[k * HID + n] : 0.f;
      ((__hip_bfloat16*)(ws + WS_WIT))[j] = __float2bfloat16(v);
    } else if (i < 1695232) {
      int j = i - 1465856;
      int n = j >> 9, k = j & 511;
      float v = (n < DIMV) ? wo[k * DIMV + n] : 0.f;
      ((__hip_bfloat16*)(ws + WS_WOT))[j] = __float2bfloat16(v);
    } else if (i < 1957376) {
      int j = (i - 1695232) * 4;
      float4 v = *(const float4*)&fg[j];
      union { __hip_bfloat16 h[4]; uint2 u; } pk;
      pk.h[0] = __float2bfloat16(v.x); pk.h[1] = __float2bfloat16(v.y);
      pk.h[2] = __float2bfloat16(v.z); pk.h[3] = __float2bfloat16(v.w);
      *(uint2*)(((__hip_bfloat16*)(ws + WS_FG16)) + j) = pk.u;
    } else {
      int j = (i - 1957376) * 4;
      float4 v = *(const float4*)&hg[j];
      union { __hip_bfloat16 h[4]; uint2 u; } pk;
      pk.h[0] = __float2bfloat16(v.x); pk.h[1] = __float2bfloat16(v.y);
      pk.h[2] = __float2bfloat16(v.z); pk.h[3] = __float2bfloat16(v.w);
      *(uint2*)(((__hip_bfloat16*)(ws + WS_HG16)) + j) = pk.u;
    }
    return;
  }

  // ---- cv part ----
  const int wv = t >> 6, lane = t & 63;
  const int wm = wv & 1, wn = wv >> 1;
  const int quad = lane >> 4, nl = lane & 15;
  const int p0 = (bx & 63) * 64, m0 = (bx >> 6) * 32;
  f32x4 acc0 = {0.f, 0.f, 0.f, 0.f};
  f32x4 acc1 = {0.f, 0.f, 0.f, 0.f};

  for (int k0 = 0; k0 < 256; k0 += 32) {
    {
      int r = t >> 3, c = t & 7;
      float4 v = *(const float4*)&qf[(m0 + r) * 256 + k0 + c * 4];
      union { __hip_bfloat16 h[4]; uint2 u; } pk;
      pk.h[0] = __float2bfloat16(v.x); pk.h[1] = __float2bfloat16(v.y);
      pk.h[2] = __float2bfloat16(v.z); pk.h[3] = __float2bfloat16(v.w);
      *(uint2*)&A_s[r * 32 + c * 4] = pk.u;
    }
    {
      int r = t >> 2, c = t & 3;
      const float* src = &fg[(p0 + r) * 256 + k0 + c * 8];
      float4 v0 = *(const float4*)src;
      float4 v1 = *(const float4*)(src + 4);
      union { __hip_bfloat16 h[8]; uint4 u; } pk;
      pk.h[0] = __float2bfloat16(v0.x); pk.h[1] = __float2bfloat16(v0.y);
      pk.h[2] = __float2bfloat16(v0.z); pk.h[3] = __float2bfloat16(v0.w);
      pk.h[4] = __float2bfloat16(v1.x); pk.h[5] = __float2bfloat16(v1.y);
      pk.h[6] = __float2bfloat16(v1.z); pk.h[7] = __float2bfloat16(v1.w);
      *(uint4*)&B_s[r * 32 + c * 8] = pk.u;
    }
    __syncthreads();
    bf16x8 a = *(const bf16x8*)&A_s[(16 * wm + nl) * 32 + quad * 8];
    bf16x8 b0 = *(const bf16x8*)&B_s[(32 * wn + nl) * 32 + quad * 8];
    bf16x8 b1 = *(const bf16x8*)&B_s[(32 * wn + 16 + nl) * 32 + quad * 8];
    acc0 = __builtin_amdgcn_mfma_f32_16x16x32_bf16(a, b0, acc0, 0, 0, 0);
    acc1 = __builtin_amdgcn_mfma_f32_16x16x32_bf16(a, b1, acc1, 0, 0, 0);
    __syncthreads();
  }
  __hip_bfloat16* cvb = (__hip_bfloat16*)ws;
#pragma unroll
  for (int nt = 0; nt < 2; nt++) {
    int n = p0 + 32 * wn + nt * 16 + nl;
#pragma unroll
    for (int r = 0; r < 4; r++) {
      int m = m0 + 16 * wm + quad * 4 + r;
      cvb[m * 4096 + n] = __float2bfloat16(nt ? acc1[r] : acc0[r]);
    }
  }
}

// ---------------------------------------------------------------------------
// head stripe kernel: 1 block = (query, 4-row stripe). 16384 blocks.
// occ stored bf16 in swizzled [r][x][ch] layout; hid3 AND hid2 consume it
// via b128 A-fragment reads + MFMA (hid2: w2 broadcast across all 16 N
// columns, so every lane's C value is a valid pmap logit).
// ---------------------------------------------------------------------------
__global__ __launch_bounds__(256, 5) void k_head_stripe(
    const float* __restrict__ h1w, const float* __restrict__ h1b,
    const float* __restrict__ h2b, const float* __restrict__ h3b,
    float* __restrict__ ws) {
  __shared__ float cvs[8 * CVP];             // cv rows y0-2..y0+5, x -1..66
  __shared__ float4 occ_t4[6 * ROWP / 16];   // bf16 occ, swizzled [r][x][ch]
  char* occ_t = (char*)occ_t4;

  const int bx = blockIdx.x;
  const int q = bx >> 4, st = bx & 15;
  const int y0 = st * 4;
  const int t = threadIdx.x;
  const int wv = t >> 6, lane = t & 63;
  const int role = (wv + bx) & 3;
  const __hip_bfloat16* cvb = (const __hip_bfloat16*)ws + q * 4096;

  // zero x-pad regions (idx 0..3 / 68..71) of all 6 rows. XOR swizzle stays
  // within each 128B group, so linear zeroing covers them.
  if (t < 192) {
    int r = t >> 5, j = t & 31;
    int off = r * ROWP + ((j < 16) ? j * 8 : 2176 + (j - 16) * 8);
    *(uint2*)(occ_t + off) = make_uint2(0u, 0u);
  }
  // out-of-range occ row (st==0: r=0 ; st==15: r=5 = y 64)
  if (st == 0 || st == 15) {
    int r = (st == 0) ? 0 : 5;
    for (int i = t; i < 288; i += 256)
      *(uint2*)(occ_t + r * ROWP + i * 8) = make_uint2(0u, 0u);
  }
  // cv stripe load (bf16 -> f32)
#pragma unroll
  for (int j = 0; j < 2; j++) {
    int i = t + 256 * j;
    int lr = i >> 6, x = i & 63;
    int g = y0 - 2 + lr;
    cvs[lr * CVP + x + 1] =
        (g >= 0 && g < 64) ? __bfloat162float(cvb[g * 64 + x]) : 0.f;
  }
  if (t < 32) {
    int rr = t >> 2, c = t & 3;
    cvs[rr * CVP + ((c == 0) ? 0 : (64 + c))] = 0.f;  // idx 0,65,66,67
  }
  __syncthreads();

  // ---- P1: hid1 conv, 1 px/lane, rolling 3x3 window, wave = 4 channels ----
  {
    const int x = lane;
    const int chg = wv * 4;
    float w1r[4][9], b1r[4];
#pragma unroll
    for (int k = 0; k < 4; k++) {
      b1r[k] = h1b[chg + k];
#pragma unroll
      for (int j = 0; j < 9; j++) w1r[k][j] = h1w[(chg + k) * 9 + j];
    }
    float win[3][3];
#pragma unroll
    for (int j = 0; j < 3; j++) {
      const float* cp = &cvs[j * CVP + x];
      win[j][0] = cp[0]; win[j][1] = cp[1]; win[j][2] = cp[2];
    }
    for (int r = 0; r < 6; r++) {
      if (r > 0) {
#pragma unroll
        for (int c = 0; c < 3; c++) { win[0][c] = win[1][c]; win[1][c] = win[2][c]; }
        const float* cp = &cvs[(r + 2) * CVP + x];
        win[2][0] = cp[0]; win[2][1] = cp[1]; win[2][2] = cp[2];
      }
      int yo = y0 - 1 + r;
      if (yo >= 0 && yo <= 63) {
        union { __hip_bfloat16 h[4]; uint2 u; } pk;
#pragma unroll
        for (int k = 0; k < 4; k++) {
          float a = b1r[k];
#pragma unroll
          for (int ky = 0; ky < 3; ky++)
            a += w1r[k][3 * ky] * win[ky][0] + w1r[k][3 * ky + 1] * win[ky][1] +
                 w1r[k][3 * ky + 2] * win[ky][2];
          pk.h[k] = __float2bfloat16(fmaxf(a, 0.f));
        }
        *(uint2*)(occ_t + occ_off(r, x + 4, chg)) = pk.u;
      }
    }
  }
  __syncthreads();

  const int nl = lane & 15;
  const int qd = lane >> 4, qh = qd >> 1, ql = qd & 1;

  if (role == 1 || role == 2) {
    // ---- hid3 MFMA: one output row (oyl = role-1). M=32 ox, N=32 oc, K=160.
    const __hip_bfloat16* W3B = (const __hip_bfloat16*)(ws + WS_W3B);
    const int oyl = role - 1;
    f32x4 acc00 = {0.f,0.f,0.f,0.f}, acc01 = {0.f,0.f,0.f,0.f};
    f32x4 acc10 = {0.f,0.f,0.f,0.f}, acc11 = {0.f,0.f,0.f,0.f};
#pragma unroll
    for (int kt = 0; kt < 5; kt++) {
      int tap = kt * 2 + qh;               // 0..9 (9 => zero pad)
      bf16x8 a0, a1;
      if (tap < 9) {
        int ky = (tap >= 6) ? 2 : ((tap >= 3) ? 1 : 0);
        int kx = tap - 3 * ky;
        int R = 2 * oyl + 1 + ky;
        int idx0 = 4 + kx + 2 * nl;
        a0 = *(const bf16x8*)(occ_t + occ_off(R, idx0, ql * 8));
        a1 = *(const bf16x8*)(occ_t + occ_off(R, idx0 + 32, ql * 8));
      } else {
        a0 = (bf16x8){0, 0, 0, 0, 0, 0, 0, 0};
        a1 = a0;
      }
      bf16x8 b0 = *(const bf16x8*)&W3B[((kt * 2 + 0) * 16 + nl) * 32 + qd * 8];
      bf16x8 b1 = *(const bf16x8*)&W3B[((kt * 2 + 1) * 16 + nl) * 32 + qd * 8];
      acc00 = __builtin_amdgcn_mfma_f32_16x16x32_bf16(a0, b0, acc00, 0, 0, 0);
      acc01 = __builtin_amdgcn_mfma_f32_16x16x32_bf16(a0, b1, acc01, 0, 0, 0);
      acc10 = __builtin_amdgcn_mfma_f32_16x16x32_bf16(a1, b0, acc10, 0, 0, 0);
      acc11 = __builtin_amdgcn_mfma_f32_16x16x32_bf16(a1, b1, acc11, 0, 0, 0);
    }
    float bb0 = h3b[nl], bb1 = h3b[16 + nl];
    float s0 = 0.f, s1 = 0.f;
#pragma unroll
    for (int r = 0; r < 4; r++) {
      s0 += fmaxf(acc00[r] + bb0, 0.f) + fmaxf(acc10[r] + bb0, 0.f);
      s1 += fmaxf(acc01[r] + bb1, 0.f) + fmaxf(acc11[r] + bb1, 0.f);
    }
    s0 += __shfl_xor(s0, 16); s0 += __shfl_xor(s0, 32);
    s1 += __shfl_xor(s1, 16); s1 += __shfl_xor(s1, 32);
    if (lane < 16) {
      atomicAdd(&ws[WS_SUM3 + (q * 16 + st) * 32 + nl], s0);
      atomicAdd(&ws[WS_SUM3 + (q * 16 + st) * 32 + 16 + nl], s1);
    }
  } else {
    // ---- hid2 via MFMA on rows rl0, rl0+1 (128 px = 8 tiles x 5 k-steps).
    const int rl0 = (role == 3) ? 2 : 0;
    const __hip_bfloat16* W2B = (const __hip_bfloat16*)(ws + WS_W2B);
    bf16x8 wb0 = *(const bf16x8*)&W2B[(0 * 16 + nl) * 32 + qd * 8];
    bf16x8 wb1 = *(const bf16x8*)&W2B[(1 * 16 + nl) * 32 + qd * 8];
    bf16x8 wb2 = *(const bf16x8*)&W2B[(2 * 16 + nl) * 32 + qd * 8];
    bf16x8 wb3 = *(const bf16x8*)&W2B[(3 * 16 + nl) * 32 + qd * 8];
    bf16x8 wb4 = *(const bf16x8*)&W2B[(4 * 16 + nl) * 32 + qd * 8];
    f32x4 pa0 = {0.f,0.f,0.f,0.f}, pa1 = {0.f,0.f,0.f,0.f};
    f32x4 pa2 = {0.f,0.f,0.f,0.f}, pa3 = {0.f,0.f,0.f,0.f};
    f32x4 pa4 = {0.f,0.f,0.f,0.f}, pa5 = {0.f,0.f,0.f,0.f};
    f32x4 pa6 = {0.f,0.f,0.f,0.f}, pa7 = {0.f,0.f,0.f,0.f};

#define H2STEP(ACC, ROW, XT, KT, WB)                                         \
    {                                                                        \
      int tap = (KT) * 2 + qh;                                               \
      bf16x8 a;                                                              \
      if (tap < 9) {                                                         \
        int ky = (tap >= 6) ? 2 : ((tap >= 3) ? 1 : 0);                      \
        int kx = tap - 3 * ky;                                               \
        a = *(const bf16x8*)(occ_t +                                         \
            occ_off((ROW) + ky, (XT) + nl + 3 + kx, ql * 8));                \
      } else { a = (bf16x8){0, 0, 0, 0, 0, 0, 0, 0}; }                       \
      ACC = __builtin_amdgcn_mfma_f32_16x16x32_bf16(a, WB, ACC, 0, 0, 0);    \
    }
#define H2TILE(ACC, ROW, XT)                                                 \
    H2STEP(ACC, ROW, XT, 0, wb0) H2STEP(ACC, ROW, XT, 1, wb1)                \
    H2STEP(ACC, ROW, XT, 2, wb2) H2STEP(ACC, ROW, XT, 3, wb3)                \
    H2STEP(ACC, ROW, XT, 4, wb4)

    H2TILE(pa0, rl0, 0)      H2TILE(pa1, rl0, 16)
    H2TILE(pa2, rl0, 32)     H2TILE(pa3, rl0, 48)
    H2TILE(pa4, rl0 + 1, 0)  H2TILE(pa5, rl0 + 1, 16)
    H2TILE(pa6, rl0 + 1, 32) H2TILE(pa7, rl0 + 1, 48)
#undef H2TILE
#undef H2STEP

    const float bb = h2b[0];
    float mg = -1e30f;
#pragma unroll
    for (int r = 0; r < 4; r++) {
      mg = fmaxf(mg, fmaxf(fmaxf(pa0[r], pa1[r]), fmaxf(pa2[r], pa3[r])));
      mg = fmaxf(mg, fmaxf(fmaxf(pa4[r], pa5[r]), fmaxf(pa6[r], pa7[r])));
    }
    mg = (mg + bb) * TEMPF;
    mg = fmaxf(mg, __shfl_xor(mg, 16));
    mg = fmaxf(mg, __shfl_xor(mg, 32));
    float sa = 0.f, sb = 0.f, sx = 0.f;
    const float fq = (float)(qd * 4);
#pragma unroll
    for (int r = 0; r < 4; r++) {
      float xr = fq + (float)r;
      float e;
      e = __expf((pa0[r] + bb) * TEMPF - mg); sa += e; sx += e * (xr + 0.f);
      e = __expf((pa1[r] + bb) * TEMPF - mg); sa += e; sx += e * (xr + 16.f);
      e = __expf((pa2[r] + bb) * TEMPF - mg); sa += e; sx += e * (xr + 32.f);
      e = __expf((pa3[r] + bb) * TEMPF - mg); sa += e; sx += e * (xr + 48.f);
      e = __expf((pa4[r] + bb) * TEMPF - mg); sb += e; sx += e * (xr + 0.f);
      e = __expf((pa5[r] + bb) * TEMPF - mg); sb += e; sx += e * (xr + 16.f);
      e = __expf((pa6[r] + bb) * TEMPF - mg); sb += e; sx += e * (xr + 32.f);
      e = __expf((pa7[r] + bb) * TEMPF - mg); sb += e; sx += e * (xr + 48.f);
    }
    float ya = (float)(y0 + rl0);
    float s = sa + sb;
    float sy = ya * sa + (ya + 1.f) * sb;
    // reduce across qd (xor 16, 32): each qd covers a disjoint x subset
    s += __shfl_xor(s, 16); sx += __shfl_xor(sx, 16); sy += __shfl_xor(sy, 16);
    s += __shfl_xor(s, 32); sx += __shfl_xor(sx, 32); sy += __shfl_xor(sy, 32);
    if (lane == 0) {
      int slot = q * 32 + st * 2 + ((role == 3) ? 1 : 0);
      *(float4*)&ws[WS_PART + slot * 4] = make_float4(mg, s, sx, sy);
    }
  }
}

// ---------------------------------------------------------------------------
// head merge only (256 blocks)
// ---------------------------------------------------------------------------
__global__ __launch_bounds__(256) void k_merge(
    const float* __restrict__ w4, const float* __restrict__ b4,
    const float* __restrict__ w5, const float* __restrict__ b5,
    float* __restrict__ ws) {
  __shared__ float sums_s[4][32];
  __shared__ float o4s[4][16];
  int t = threadIdx.x, wv = t >> 6, lane = t & 63;
  int q = blockIdx.x * 4 + wv;

  float M = -1e30f, S = 0.f, SX = 0.f, SY = 0.f;
  if (lane < 32) {
    float4 pv = *(const float4*)&ws[WS_PART + (q * 32 + lane) * 4];
    M = pv.x; S = pv.y; SX = pv.z; SY = pv.w;
  }
#pragma unroll
  for (int off = 1; off < 64; off <<= 1) {
    float Mo = __shfl_xor(M, off), So = __shfl_xor(S, off);
    float SXo = __shfl_xor(SX, off), SYo = __shfl_xor(SY, off);
    float Mn = fmaxf(M, Mo);
    float c1 = __expf(M - Mn), c2 = __expf(Mo - Mn);
    S = S * c1 + So * c2; SX = SX * c1 + SXo * c2; SY = SY * c1 + SYo * c2;
    M = Mn;
  }
  if (lane == 0) {
    ws[WS_POS + q * 2 + 0] = (SX / S) * 8.0f;
    ws[WS_POS + q * 2 + 1] = (SY / S) * 8.0f;
  }

  int ch = lane & 31, half = lane >> 5;
  float sm = 0.f;
#pragma unroll
  for (int s8 = 0; s8 < 8; s8++)
    sm += ws[WS_SUM3 + (q * 16 + half * 8 + s8) * 32 + ch];
  sm += __shfl_xor(sm, 32);
  if (lane < 32) sums_s[wv][lane] = sm * (1.f / 1024.f);
  __syncthreads();
  if (lane < 16) {
    float a = b4[lane];
#pragma unroll
    for (int i = 0; i < 32; i++) a += sums_s[wv][i] * w4[i * 16 + lane];
    o4s[wv][lane] = fmaxf(a, 0.f);
  }
  __syncthreads();
  if (lane < 2) {
    float r = b5[lane];
#pragma unroll
    for (int j = 0; j < 16; j++) r += o4s[wv][j] * w5[j * 2 + lane];
    __hip_bfloat16* mi = (__hip_bfloat16*)(ws + WS_MLPIN);
    if (lane == 0) { ws[WS_OCC + q] = r;  mi[q * KPAD + 2] = __float2bfloat16(r); }
    else           { ws[WS_EXPD + q] = r; mi[q * KPAD + 3] = __float2bfloat16(r); }
  }
}

// ---------------------------------------------------------------------------
// correlation (bf16 grids). 1 block = 1 query; writes only corr cols.
// ---------------------------------------------------------------------------
__global__ __launch_bounds__(256) void k_corr(float* __restrict__ ws) {
  __shared__ float qs[384];
  __shared__ float dbuf[3][64];
  int t = threadIdx.x;
  int wv = t >> 6, lane = t & 63;
  int cl = lane & 15, sub = lane >> 4;
  int n = blockIdx.x;
  const float* feats = ws + WS_FEATS + n * 384;
  float posx = ws[WS_POS + n * 2 + 0];
  float posy = ws[WS_POS + n * 2 + 1];
  __hip_bfloat16* mi = (__hip_bfloat16*)(ws + WS_MLPIN) + n * KPAD;

  for (int col = t; col < 384; col += 256) qs[col] = feats[col];
  __syncthreads();

  float qh[8], qq[16];
#pragma unroll
  for (int j = 0; j < 8; j++) qh[j] = qs[cl * 8 + j];
#pragma unroll
  for (int j = 0; j < 16; j++) qq[j] = qs[128 + cl * 16 + j];

  const __hip_bfloat16* G0 = (const __hip_bfloat16*)(ws + WS_HG16);
  const __hip_bfloat16* G1 = (const __hip_bfloat16*)(ws + WS_FG16);
  const __hip_bfloat16* G2 = (const __hip_bfloat16*)(ws + WS_AV16);

#pragma unroll
  for (int L = 0; L < 3; L++) {
    const __hip_bfloat16* grid;
    int Hg, Wg;
    float scl;
    if (L == 0)      { grid = G0; Hg = 128; Wg = 128; scl = 0.25f; }
    else if (L == 1) { grid = G1; Hg = 64;  Wg = 64;  scl = 0.125f; }
    else             { grid = G2; Hg = 32;  Wg = 32;  scl = 0.0625f; }
    float cy = posy * scl, cx = posx * scl;
    int iy = (int)floorf(cy), ix = (int)floorf(cx);
#pragma unroll
    for (int g = 0; g < 4; g++) {
      int p = wv * 16 + g * 4 + sub;
      int a = p >> 3, b = p & 7;
      int row = iy + a - 3; row = row < 0 ? 0 : (row > Hg - 1 ? Hg - 1 : row);
      int col = ix + b - 3; col = col < 0 ? 0 : (col > Wg - 1 ? Wg - 1 : col);
      float acc = 0.f;
      if (L == 0) {
        BU8 g0; g0.u = *(const uint4*)(grid + (row * Wg + col) * 128 + cl * 8);
#pragma unroll
        for (int j = 0; j < 8; j++) acc += __bfloat162float(g0.h[j]) * qh[j];
      } else {
        const __hip_bfloat16* gp = grid + (row * Wg + col) * 256 + cl * 16;
        BU8 g0, g1;
        g0.u = *(const uint4*)gp;
        g1.u = *(const uint4*)(gp + 8);
#pragma unroll
        for (int j = 0; j < 8; j++) {
          acc += __bfloat162float(g0.h[j]) * qq[j];
          acc += __bfloat162float(g1.h[j]) * qq[8 + j];
        }
      }
      acc += __shfl_xor(acc, 1);
      acc += __shfl_xor(acc, 2);
      acc += __shfl_xor(acc, 4);
      acc += __shfl_xor(acc, 8);
      if (cl == 0) dbuf[L][p] = acc;
    }
  }
  __syncthreads();

  if (t < 147) {
    int L = t / 49, s = t - L * 49;
    int sa = s / 7, sb = s - sa * 7;
    float scl = (L == 0) ? 0.25f : ((L == 1) ? 0.125f : 0.0625f);
    float cy = posy * scl, cx = posx * scl;
    float wy = cy - floorf(cy), wx = cx - floorf(cx);
    int i00 = sa * 8 + sb;
    float d00 = dbuf[L][i00], d01 = dbuf[L][i00 + 1];
    float d10 = dbuf[L][i00 + 8], d11 = dbuf[L][i00 + 9];
    float corr = (1.f - wy) * (1.f - wx) * d00 + (1.f - wy) * wx * d01 +
                 wy * (1.f - wx) * d10 + wy * wx * d11;
    mi[388 + t] = __float2bfloat16(corr);
  }
}

// ---------------------------------------------------------------------------
__device__ __forceinline__ float gelu_tanh(float x) {
  float z = 0.7978845608028654f * (x + 0.044715f * x * x * x);
  z = fminf(fmaxf(z, -15.f), 15.f);
  float e = __expf(2.f * z);
  float th = (e - 1.f) / (e + 1.f);
  return 0.5f * x * (1.f + th);
}

// ---------------------------------------------------------------------------
// mixer GEMM 1, barrier-free: 1 wave = one 16x16 tile, direct-global frags.
// ---------------------------------------------------------------------------
__global__ __launch_bounds__(256) void k_mix1(
    const float* __restrict__ bias, float* __restrict__ ws) {
  const int t = threadIdx.x;
  const int wv = t >> 6, lane = t & 63;
  const int nt = blockIdx.x * 4 + wv;
  const int mt = blockIdx.y;
  const int m0 = mt * 16, n0 = nt * 16;
  const int nl = lane & 15, quad = lane >> 4;
  const unsigned short* Abf = (const unsigned short*)(ws + WS_MLPIN);
  const unsigned short* WIT = (const unsigned short*)(ws + WS_WIT);
  const unsigned short* ap = &Abf[(m0 + nl) * KPAD + quad * 8];
  const unsigned short* bp = &WIT[(n0 + nl) * KPAD + quad * 8];
  f32x4 acc = {0.f, 0.f, 0.f, 0.f};
#pragma unroll
  for (int ks = 0; ks < 17; ks++) {
    bf16x8 a = *(const bf16x8*)(ap + ks * 32);
    bf16x8 b = *(const bf16x8*)(bp + ks * 32);
    acc = __builtin_amdgcn_mfma_f32_16x16x32_bf16(a, b, acc, 0, 0, 0);
  }
  __hip_bfloat16* Hd = (__hip_bfloat16*)(ws + WS_HIDDEN);
  int nn = n0 + nl;
  float bv = bias[nn];
#pragma unroll
  for (int r = 0; r < 4; r++) {
    int m = m0 + quad * 4 + r;
    Hd[m * HID + nn] = __float2bfloat16(gelu_tanh(acc[r] + bv));
  }
}

// ---------------------------------------------------------------------------
// mixer GEMM 2, barrier-free + state update + out write.
// ---------------------------------------------------------------------------
__global__ __launch_bounds__(256) void k_mix2(
    const float* __restrict__ bias, float* __restrict__ ws,
    float* __restrict__ out) {
  const int t = threadIdx.x;
  const int wv = t >> 6, lane = t & 63;
  const int nt = blockIdx.x * 4 + wv;
  const int mt = blockIdx.y;
  const int m0 = mt * 16, n0 = nt * 16;
  const int nl = lane & 15, quad = lane >> 4;
  const unsigned short* Abf = (const unsigned short*)(ws + WS_HIDDEN);
  const unsigned short* WOT = (const unsigned short*)(ws + WS_WOT);
  const unsigned short* ap = &Abf[(m0 + nl) * HID + quad * 8];
  const unsigned short* bp = &WOT[(n0 + nl) * HID + quad * 8];
  f32x4 acc = {0.f, 0.f, 0.f, 0.f};
#pragma unroll
  for (int ks = 0; ks < 16; ks++) {
    bf16x8 a = *(const bf16x8*)(ap + ks * 32);
    bf16x8 b = *(const bf16x8*)(bp + ks * 32);
    acc = __builtin_amdgcn_mfma_f32_16x16x32_bf16(a, b, acc, 0, 0, 0);
  }

  int col = n0 + nl;
  if (col < DIMV) {
    float bv = bias[col];
    __hip_bfloat16* mib = (__hip_bfloat16*)(ws + WS_MLPIN);
#pragma unroll
    for (int r = 0; r < 4; r++) {
      int m = m0 + quad * 4 + r;
      float rr = acc[r] + bv;
      if (col < 2) {
        float v = ws[WS_POS + m * 2 + col] + rr;
        ws[WS_POS + m * 2 + col] = v;
        out[m * 4 + col] = v;
      } else if (col == 2) {
        float v = ws[WS_OCC + m] + rr;
        ws[WS_OCC + m] = v;
        out[m * 4 + 2] = v;
        mib[m * KPAD + 2] = __float2bfloat16(v);
      } else if (col == 3) {
        float v = ws[WS_EXPD + m] + rr;
        ws[WS_EXPD + m] = v;
        out[m * 4 + 3] = v;
        mib[m * KPAD + 3] = __float2bfloat16(v);
      } else {
        float v = ws[WS_FEATS + m * 384 + (col - 4)] + rr;
        ws[WS_FEATS + m * 384 + (col - 4)] = v;
        mib[m * KPAD + col] = __float2bfloat16(v);
      }
    }
  }
}

// ---------------------------------------------------------------------------
extern "C" void kernel_launch(void* const* d_in, const int* in_sizes, int n_in,
                              void* d_out, int out_size, void* d_ws, size_t ws_size,
                              hipStream_t stream) {
  const float* fg = (const float*)d_in[0];
  const float* hg = (const float*)d_in[1];
  const float* qf = (const float*)d_in[2];
  const float* hq = (const float*)d_in[3];
  const float* w1 = (const float*)d_in[4];
  const float* b1 = (const float*)d_in[5];
  const float* w2 = (const float*)d_in[6];
  const float* b2 = (const float*)d_in[7];
  const float* w3 = (const float*)d_in[8];
  const float* b3 = (const float*)d_in[9];
  const float* w4 = (const float*)d_in[10];
  const float* b4 = (const float*)d_in[11];
  const float* w5 = (const float*)d_in[12];
  const float* b5 = (const float*)d_in[13];
  const float* wi = (const float*)d_in[14];
  const float* bi = (const float*)d_in[15];
  const float* wo = (const float*)d_in[16];
  const float* bo = (const float*)d_in[17];
  float* ws = (float*)d_ws;
  float* out = (float*)d_out;

  k_prep_cv<<<11742, 256, 0, stream>>>(fg, hg, qf, hq, w3, w2, wi, wo, ws);
  k_head_stripe<<<16384, 256, 0, stream>>>(w1, b1, b2, b3, ws);
  k_merge<<<256, 256, 0, stream>>>(w4, b4, w5, b5, ws);
  for (int it = 0; it < 4; it++) {
    k_corr<<<1024, 256, 0, stream>>>(ws);
    k_mix1<<<dim3(8, 64), 256, 0, stream>>>(bi, ws);
    k_mix2<<<dim3(7, 64), 256, 0, stream>>>(bo, ws, out);
  }
}